// Round 3
// baseline (496.529 us; speedup 1.0000x reference)
//
#include <hip/hip_runtime.h>
#include <math.h>

// Problem constants (fixed by the reference)
static constexpr int NN  = 50000;   // nodes
static constexpr int NE  = 600000;  // edges
static constexpr int HD  = 128;     // feature dim
static constexpr int NL  = 4;       // layers
static constexpr int NB  = 256;     // graphs
static constexpr int NM  = 200;     // molecule features
static constexpr int NO  = 12;      // out features
static constexpr int NMH = 32;      // molecular head width

#define FMA4(ac, s, b) { (ac).x += (s)*(b).x; (ac).y += (s)*(b).y; (ac).z += (s)*(b).z; (ac).w += (s)*(b).w; }

// ---------------- CSR build ----------------
__global__ void k_hist(const int* __restrict__ dst, int* __restrict__ counts) {
  int e = blockIdx.x * blockDim.x + threadIdx.x;
  if (e < NE) atomicAdd(&counts[dst[e]], 1);
}

__global__ void k_dis(const int* __restrict__ counts, float* __restrict__ dis) {
  int i = blockIdx.x * blockDim.x + threadIdx.x;
  if (i < NN) dis[i] = rsqrtf((float)(counts[i] + 1));
}

// per-block inclusive scan; writes local inclusive scan into incl, block totals into bsum
__global__ void k_scan1(const int* __restrict__ counts, int* __restrict__ incl, int* __restrict__ bsum) {
  __shared__ int s[256];
  int i = blockIdx.x * 256 + threadIdx.x;
  int v = (i < NN) ? counts[i] : 0;
  s[threadIdx.x] = v;
  __syncthreads();
  for (int off = 1; off < 256; off <<= 1) {
    int t = (threadIdx.x >= off) ? s[threadIdx.x - off] : 0;
    __syncthreads();
    s[threadIdx.x] += t;
    __syncthreads();
  }
  if (i < NN) incl[i] = s[threadIdx.x];
  if (threadIdx.x == 255) bsum[blockIdx.x] = s[255];
}

// single block: exclusive scan of up to 256 block sums
__global__ void k_scan2(const int* __restrict__ bsum, int* __restrict__ boff, int nblocks) {
  __shared__ int s[256];
  int v = (threadIdx.x < nblocks) ? bsum[threadIdx.x] : 0;
  s[threadIdx.x] = v;
  __syncthreads();
  for (int off = 1; off < 256; off <<= 1) {
    int t = (threadIdx.x >= off) ? s[threadIdx.x - off] : 0;
    __syncthreads();
    s[threadIdx.x] += t;
    __syncthreads();
  }
  boff[threadIdx.x] = s[threadIdx.x] - v;  // exclusive
}

__global__ void k_scan3(const int* __restrict__ counts, int* __restrict__ rowst, const int* __restrict__ boff) {
  int i = blockIdx.x * 256 + threadIdx.x;
  if (i < NN) {
    rowst[i] = rowst[i] - counts[i] + boff[blockIdx.x];  // exclusive global
    if (i == NN - 1) rowst[NN] = NE;
  }
}

__global__ void k_fill(const int* __restrict__ src, const int* __restrict__ dst,
                       const int* __restrict__ rowst, int* __restrict__ cur, int* __restrict__ csr) {
  int e = blockIdx.x * blockDim.x + threadIdx.x;
  if (e < NE) {
    int d = dst[e];
    int p = atomicAdd(&cur[d], 1);
    csr[rowst[d] + p] = src[e];
  }
}

// ---------------- misc ----------------
__global__ void k_copy4(const float4* __restrict__ a, float4* __restrict__ b, int n4) {
  int i = blockIdx.x * blockDim.x + threadIdx.x;
  if (i < n4) b[i] = a[i];
}

__global__ void k_goffs(const int* __restrict__ batch, int* __restrict__ goffs) {
  int i = blockIdx.x * blockDim.x + threadIdx.x;
  if (i >= NN) return;
  int b = batch[i];
  if (i == 0) {
    for (int g = 0; g <= b; ++g) goffs[g] = 0;
  } else {
    int pb = batch[i - 1];
    for (int g = pb + 1; g <= b; ++g) goffs[g] = i;
  }
  if (i == NN - 1) goffs[NB] = NN;
}

// ---------------- GEMM: C[NN,128] = A[NN,128] @ W[128,128] ----------------
__launch_bounds__(256)
__global__ void k_gemm(const float* __restrict__ A, const float* __restrict__ W,
                       float* __restrict__ C) {
  __shared__ float At[16][68];   // transposed A tile, padded stride 68 (16B-aligned rows)
  __shared__ float Bt[16][128];

  const int t = threadIdx.x;
  const int tc = t & 15;         // col group: cols {tc*4..+3, 64+tc*4..+3}
  const int tr = t >> 4;         // row group 0..15: rows tr*4..tr*4+3
  const int row0 = blockIdx.x * 64 + tr * 4;
  const int lrow = t >> 2;       // 0..63 (A-load row)
  const int lc = t & 3;          // 0..3  (A-load k-chunk)
  const int grow = blockIdx.x * 64 + lrow;

  float4 acc0[4], acc1[4];
#pragma unroll
  for (int i = 0; i < 4; ++i) { acc0[i] = make_float4(0,0,0,0); acc1[i] = make_float4(0,0,0,0); }

  for (int k0 = 0; k0 < HD; k0 += 16) {
    float4 av = make_float4(0,0,0,0);
    if (grow < NN) av = *(const float4*)&A[(size_t)grow * HD + k0 + lc * 4];
    float4 bv0 = *(const float4*)&W[k0 * HD + t * 4];
    float4 bv1 = *(const float4*)&W[k0 * HD + 1024 + t * 4];

    __syncthreads();
    At[lc * 4 + 0][lrow] = av.x;
    At[lc * 4 + 1][lrow] = av.y;
    At[lc * 4 + 2][lrow] = av.z;
    At[lc * 4 + 3][lrow] = av.w;
    {
      int f0 = t * 4;           // [0,1024): rows 0..7
      int f1 = (t + 256) * 4;   // rows 8..15
      *(float4*)&Bt[f0 >> 7][f0 & 127] = bv0;
      *(float4*)&Bt[f1 >> 7][f1 & 127] = bv1;
    }
    __syncthreads();

#pragma unroll
    for (int kk = 0; kk < 16; ++kk) {
      float4 a  = *(const float4*)&At[kk][tr * 4];
      float4 b0 = *(const float4*)&Bt[kk][tc * 4];
      float4 b1 = *(const float4*)&Bt[kk][64 + tc * 4];
      FMA4(acc0[0], a.x, b0); FMA4(acc0[1], a.y, b0); FMA4(acc0[2], a.z, b0); FMA4(acc0[3], a.w, b0);
      FMA4(acc1[0], a.x, b1); FMA4(acc1[1], a.y, b1); FMA4(acc1[2], a.z, b1); FMA4(acc1[3], a.w, b1);
    }
  }

#pragma unroll
  for (int i = 0; i < 4; ++i) {
    int gr = row0 + i;
    if (gr < NN) {
      *(float4*)&C[(size_t)gr * HD + tc * 4]      = acc0[i];
      *(float4*)&C[(size_t)gr * HD + 64 + tc * 4] = acc1[i];
    }
  }
}

// ---------------- aggregate + bias + relu + residual (in-place h) ----------------
__global__ void k_agg(const float* __restrict__ xw, const float* __restrict__ dis,
                      const int* __restrict__ rowst, const int* __restrict__ csr,
                      const float* __restrict__ bias, float* __restrict__ h) {
  int g = threadIdx.x >> 5;          // node slot 0..7
  int lane = threadIdx.x & 31;       // feature group: floats lane*4..lane*4+3
  int n = blockIdx.x * 8 + g;
  if (n >= NN) return;

  float dn = dis[n];
  float4 acc = *(const float4*)&xw[(size_t)n * HD + lane * 4];
  float sl = dn * dn;
  acc.x *= sl; acc.y *= sl; acc.z *= sl; acc.w *= sl;

  int s0 = rowst[n], s1 = rowst[n + 1];
  for (int idx = s0; idx < s1; ++idx) {
    int s = csr[idx];
    float nm = dis[s] * dn;
    float4 v = *(const float4*)&xw[(size_t)s * HD + lane * 4];
    FMA4(acc, nm, v);
  }

  float4 b4 = *(const float4*)&bias[lane * 4];
  float4 hv = *(const float4*)&h[(size_t)n * HD + lane * 4];
  float4 out;
  out.x = fmaxf(acc.x + b4.x, 0.f) + hv.x;
  out.y = fmaxf(acc.y + b4.y, 0.f) + hv.y;
  out.z = fmaxf(acc.z + b4.z, 0.f) + hv.z;
  out.w = fmaxf(acc.w + b4.w, 0.f) + hv.w;
  *(float4*)&h[(size_t)n * HD + lane * 4] = out;
}

// ---------------- pooling: per-graph max & sum ----------------
__global__ void k_pool(const float* __restrict__ h, const int* __restrict__ goffs,
                       float* __restrict__ pooled) {
  int g = blockIdx.x;
  int t = threadIdx.x;  // 128
  int a = goffs[g], bnd = goffs[g + 1];
  float mx = -INFINITY, sm = 0.f;
  for (int i = a; i < bnd; ++i) {
    float v = h[(size_t)i * HD + t];
    mx = fmaxf(mx, v);
    sm += v;
  }
  pooled[g * 256 + t] = mx;
  pooled[g * 256 + 128 + t] = sm;
}

// ---------------- head: mol linear+BN+relu, concat, MLP ----------------
__global__ void k_head(const float* __restrict__ pooled, const float* __restrict__ mf,
                       const float* __restrict__ Wm, const float* __restrict__ bm,
                       const float* __restrict__ gamma, const float* __restrict__ beta,
                       const float* __restrict__ W1, const float* __restrict__ b1,
                       const float* __restrict__ W2, const float* __restrict__ b2,
                       float* __restrict__ out) {
  __shared__ float z[288];
  __shared__ float z1[128];
  int g = blockIdx.x, t = threadIdx.x;  // 128 threads
  z[t] = pooled[g * 256 + t];
  z[128 + t] = pooled[g * 256 + 128 + t];
  if (t < NMH) {
    float acc = bm[t];
    for (int k = 0; k < NM; ++k) acc += mf[g * NM + k] * Wm[k * NMH + t];
    acc = acc * gamma[t] + beta[t];
    z[256 + t] = fmaxf(acc, 0.f);
  }
  __syncthreads();
  float acc = b1[t];
  for (int k = 0; k < 288; ++k) acc += z[k] * W1[k * HD + t];
  z1[t] = fmaxf(acc, 0.f);
  __syncthreads();
  if (t < NO) {
    float a2 = b2[t];
    for (int k = 0; k < HD; ++k) a2 += z1[k] * W2[k * NO + t];
    out[g * NO + t] = a2;
  }
}

extern "C" void kernel_launch(void* const* d_in, const int* in_sizes, int n_in,
                              void* d_out, int out_size, void* d_ws, size_t ws_size,
                              hipStream_t stream) {
  const float* x     = (const float*)d_in[0];
  const int*   eidx  = (const int*)d_in[1];
  const int*   batch = (const int*)d_in[2];
  const float* mf    = (const float*)d_in[3];
  const float* Ws    = (const float*)d_in[4];
  const float* bs    = (const float*)d_in[5];
  const float* Wm    = (const float*)d_in[6];
  const float* bm    = (const float*)d_in[7];
  const float* gamma = (const float*)d_in[8];
  const float* beta  = (const float*)d_in[9];
  const float* W1    = (const float*)d_in[10];
  const float* b1    = (const float*)d_in[11];
  const float* W2    = (const float*)d_in[12];
  const float* b2    = (const float*)d_in[13];
  float* out = (float*)d_out;

  const int* src = eidx;
  const int* dst = eidx + NE;

  // workspace carve-out
  char* w = (char*)d_ws;
  size_t off = 0;
  auto alloc = [&](size_t bytes) -> void* {
    void* p = w + off;
    off += (bytes + 255) & ~(size_t)255;
    return p;
  };
  float* dis    = (float*)alloc((size_t)NN * 4);
  float* h      = (float*)alloc((size_t)NN * HD * 4);
  float* xw     = (float*)alloc((size_t)NN * HD * 4);
  int* counts   = (int*)alloc((size_t)NN * 4);
  int* cur      = (int*)alloc((size_t)NN * 4);
  int* rowst    = (int*)alloc((size_t)(NN + 1) * 4);
  int* csr      = (int*)alloc((size_t)NE * 4);
  int* bsum     = (int*)alloc(256 * 4);
  int* boff     = (int*)alloc(256 * 4);
  int* goffs    = (int*)alloc((size_t)(NB + 1) * 4);
  float* pooled = (float*)alloc((size_t)NB * 256 * 4);
  (void)ws_size;

  const int SB = (NN + 255) / 256;  // 196 scan blocks

  hipMemsetAsync(counts, 0, (size_t)NN * 4, stream);
  hipMemsetAsync(cur, 0, (size_t)NN * 4, stream);

  k_hist<<<(NE + 255) / 256, 256, 0, stream>>>(dst, counts);
  k_dis<<<SB, 256, 0, stream>>>(counts, dis);
  k_scan1<<<SB, 256, 0, stream>>>(counts, rowst, bsum);
  k_scan2<<<1, 256, 0, stream>>>(bsum, boff, SB);
  k_scan3<<<SB, 256, 0, stream>>>(counts, rowst, boff);
  k_fill<<<(NE + 255) / 256, 256, 0, stream>>>(src, dst, rowst, cur, csr);

  k_copy4<<<((NN * HD / 4) + 255) / 256, 256, 0, stream>>>((const float4*)x, (float4*)h, NN * HD / 4);
  k_goffs<<<SB, 256, 0, stream>>>(batch, goffs);

  for (int l = 0; l < NL; ++l) {
    k_gemm<<<(NN + 63) / 64, 256, 0, stream>>>(h, Ws + (size_t)l * HD * HD, xw);
    k_agg<<<(NN + 7) / 8, 256, 0, stream>>>(xw, dis, rowst, csr, bs + (size_t)l * HD, h);
  }

  k_pool<<<NB, 128, 0, stream>>>(h, goffs, pooled);
  k_head<<<NB, 128, 0, stream>>>(pooled, mf, Wm, bm, gamma, beta, W1, b1, W2, b2, out);
}

// Round 4
// 435.366 us; speedup vs baseline: 1.1405x; 1.1405x over previous
//
#include <hip/hip_runtime.h>
#include <math.h>

// Problem constants (fixed by the reference)
static constexpr int NN  = 50000;   // nodes
static constexpr int NE  = 600000;  // edges
static constexpr int HD  = 128;     // feature dim
static constexpr int NL  = 4;       // layers
static constexpr int NB  = 256;     // graphs
static constexpr int NM  = 200;     // molecule features
static constexpr int NO  = 12;      // out features
static constexpr int NMH = 32;      // molecular head width

#define FMA4(ac, s, b) { (ac).x += (s)*(b).x; (ac).y += (s)*(b).y; (ac).z += (s)*(b).z; (ac).w += (s)*(b).w; }
#define MAX4(ac, b) { (ac).x = fmaxf((ac).x,(b).x); (ac).y = fmaxf((ac).y,(b).y); (ac).z = fmaxf((ac).z,(b).z); (ac).w = fmaxf((ac).w,(b).w); }
#define ADD4(ac, b) { (ac).x += (b).x; (ac).y += (b).y; (ac).z += (b).z; (ac).w += (b).w; }

// ---------------- CSR build ----------------
__global__ void k_hist(const int* __restrict__ dst, int* __restrict__ counts) {
  int e = blockIdx.x * blockDim.x + threadIdx.x;
  if (e < NE) atomicAdd(&counts[dst[e]], 1);
}

__global__ void k_dis(const int* __restrict__ counts, float* __restrict__ dis) {
  int i = blockIdx.x * blockDim.x + threadIdx.x;
  if (i < NN) dis[i] = rsqrtf((float)(counts[i] + 1));
}

// per-block inclusive scan; writes local inclusive scan into incl, block totals into bsum
__global__ void k_scan1(const int* __restrict__ counts, int* __restrict__ incl, int* __restrict__ bsum) {
  __shared__ int s[256];
  int i = blockIdx.x * 256 + threadIdx.x;
  int v = (i < NN) ? counts[i] : 0;
  s[threadIdx.x] = v;
  __syncthreads();
  for (int off = 1; off < 256; off <<= 1) {
    int t = (threadIdx.x >= off) ? s[threadIdx.x - off] : 0;
    __syncthreads();
    s[threadIdx.x] += t;
    __syncthreads();
  }
  if (i < NN) incl[i] = s[threadIdx.x];
  if (threadIdx.x == 255) bsum[blockIdx.x] = s[255];
}

// single block: exclusive scan of up to 256 block sums
__global__ void k_scan2(const int* __restrict__ bsum, int* __restrict__ boff, int nblocks) {
  __shared__ int s[256];
  int v = (threadIdx.x < nblocks) ? bsum[threadIdx.x] : 0;
  s[threadIdx.x] = v;
  __syncthreads();
  for (int off = 1; off < 256; off <<= 1) {
    int t = (threadIdx.x >= off) ? s[threadIdx.x - off] : 0;
    __syncthreads();
    s[threadIdx.x] += t;
    __syncthreads();
  }
  boff[threadIdx.x] = s[threadIdx.x] - v;  // exclusive
}

__global__ void k_scan3(const int* __restrict__ counts, int* __restrict__ rowst, const int* __restrict__ boff) {
  int i = blockIdx.x * 256 + threadIdx.x;
  if (i < NN) {
    rowst[i] = rowst[i] - counts[i] + boff[blockIdx.x];  // exclusive global
    if (i == NN - 1) rowst[NN] = NE;
  }
}

__global__ void k_fill(const int* __restrict__ src, const int* __restrict__ dst,
                       const int* __restrict__ rowst, int* __restrict__ cur, int* __restrict__ csr) {
  int e = blockIdx.x * blockDim.x + threadIdx.x;
  if (e < NE) {
    int d = dst[e];
    int p = atomicAdd(&cur[d], 1);
    csr[rowst[d] + p] = src[e];
  }
}

// ---------------- misc ----------------
__global__ void k_goffs(const int* __restrict__ batch, int* __restrict__ goffs) {
  int i = blockIdx.x * blockDim.x + threadIdx.x;
  if (i >= NN) return;
  int b = batch[i];
  if (i == 0) {
    for (int g = 0; g <= b; ++g) goffs[g] = 0;
  } else {
    int pb = batch[i - 1];
    for (int g = pb + 1; g <= b; ++g) goffs[g] = i;
  }
  if (i == NN - 1) goffs[NB] = NN;
}

// ---------------- GEMM: C[NN,128] = A[NN,128] @ W[128,128] ----------------
__launch_bounds__(256)
__global__ void k_gemm(const float* __restrict__ A, const float* __restrict__ W,
                       float* __restrict__ C) {
  __shared__ float At[16][68];   // transposed A tile, padded stride 68 (16B-aligned rows)
  __shared__ float Bt[16][128];

  const int t = threadIdx.x;
  const int tc = t & 15;         // col group: cols {tc*4..+3, 64+tc*4..+3}
  const int tr = t >> 4;         // row group 0..15: rows tr*4..tr*4+3
  const int row0 = blockIdx.x * 64 + tr * 4;
  const int lrow = t >> 2;       // 0..63 (A-load row)
  const int lc = t & 3;          // 0..3  (A-load k-chunk)
  const int grow = blockIdx.x * 64 + lrow;

  float4 acc0[4], acc1[4];
#pragma unroll
  for (int i = 0; i < 4; ++i) { acc0[i] = make_float4(0,0,0,0); acc1[i] = make_float4(0,0,0,0); }

  for (int k0 = 0; k0 < HD; k0 += 16) {
    float4 av = make_float4(0,0,0,0);
    if (grow < NN) av = *(const float4*)&A[(size_t)grow * HD + k0 + lc * 4];
    float4 bv0 = *(const float4*)&W[k0 * HD + t * 4];
    float4 bv1 = *(const float4*)&W[k0 * HD + 1024 + t * 4];

    __syncthreads();
    At[lc * 4 + 0][lrow] = av.x;
    At[lc * 4 + 1][lrow] = av.y;
    At[lc * 4 + 2][lrow] = av.z;
    At[lc * 4 + 3][lrow] = av.w;
    {
      int f0 = t * 4;           // [0,1024): rows 0..7
      int f1 = (t + 256) * 4;   // rows 8..15
      *(float4*)&Bt[f0 >> 7][f0 & 127] = bv0;
      *(float4*)&Bt[f1 >> 7][f1 & 127] = bv1;
    }
    __syncthreads();

#pragma unroll
    for (int kk = 0; kk < 16; ++kk) {
      float4 a  = *(const float4*)&At[kk][tr * 4];
      float4 b0 = *(const float4*)&Bt[kk][tc * 4];
      float4 b1 = *(const float4*)&Bt[kk][64 + tc * 4];
      FMA4(acc0[0], a.x, b0); FMA4(acc0[1], a.y, b0); FMA4(acc0[2], a.z, b0); FMA4(acc0[3], a.w, b0);
      FMA4(acc1[0], a.x, b1); FMA4(acc1[1], a.y, b1); FMA4(acc1[2], a.z, b1); FMA4(acc1[3], a.w, b1);
    }
  }

#pragma unroll
  for (int i = 0; i < 4; ++i) {
    int gr = row0 + i;
    if (gr < NN) {
      *(float4*)&C[(size_t)gr * HD + tc * 4]      = acc0[i];
      *(float4*)&C[(size_t)gr * HD + 64 + tc * 4] = acc1[i];
    }
  }
}

// ---------------- aggregate + bias + relu + residual ----------------
// hout[n] = relu(agg + bias) + hin[n]; hin/hout may alias (in-place) or differ (layer 0)
__global__ void k_agg(const float* __restrict__ xw, const float* __restrict__ dis,
                      const int* __restrict__ rowst, const int* __restrict__ csr,
                      const float* __restrict__ bias, const float* __restrict__ hin,
                      float* __restrict__ hout) {
  int g = threadIdx.x >> 5;          // node slot 0..7
  int lane = threadIdx.x & 31;       // feature group: floats lane*4..lane*4+3
  int n = blockIdx.x * 8 + g;
  if (n >= NN) return;

  float dn = dis[n];
  float4 acc = *(const float4*)&xw[(size_t)n * HD + lane * 4];
  float sl = dn * dn;
  acc.x *= sl; acc.y *= sl; acc.z *= sl; acc.w *= sl;

  int s0 = rowst[n], s1 = rowst[n + 1];
  for (int idx = s0; idx < s1; ++idx) {
    int s = csr[idx];
    float nm = dis[s] * dn;
    float4 v = *(const float4*)&xw[(size_t)s * HD + lane * 4];
    FMA4(acc, nm, v);
  }

  float4 b4 = *(const float4*)&bias[lane * 4];
  float4 hv = *(const float4*)&hin[(size_t)n * HD + lane * 4];
  float4 out;
  out.x = fmaxf(acc.x + b4.x, 0.f) + hv.x;
  out.y = fmaxf(acc.y + b4.y, 0.f) + hv.y;
  out.z = fmaxf(acc.z + b4.z, 0.f) + hv.z;
  out.w = fmaxf(acc.w + b4.w, 0.f) + hv.w;
  *(float4*)&hout[(size_t)n * HD + lane * 4] = out;
}

// ---------------- pooling: per-graph max & sum (parallel over 32 node slots) ----------------
__launch_bounds__(1024)
__global__ void k_pool(const float* __restrict__ h, const int* __restrict__ goffs,
                       float* __restrict__ pooled) {
  __shared__ float4 smax[32][32];   // [slot][lane]
  __shared__ float4 ssum[32][32];
  int g = blockIdx.x;
  int slot = threadIdx.x >> 5;      // 0..31: node slot
  int lane = threadIdx.x & 31;      // feature group: floats lane*4..+3
  int a = goffs[g], bnd = goffs[g + 1];

  float4 mx = make_float4(-INFINITY, -INFINITY, -INFINITY, -INFINITY);
  float4 sm = make_float4(0.f, 0.f, 0.f, 0.f);
  for (int i = a + slot; i < bnd; i += 32) {
    float4 v = *(const float4*)&h[(size_t)i * HD + lane * 4];
    MAX4(mx, v);
    ADD4(sm, v);
  }
  smax[slot][lane] = mx;
  ssum[slot][lane] = sm;
  __syncthreads();
#pragma unroll
  for (int off = 16; off >= 1; off >>= 1) {
    if (slot < off) {
      float4 m2 = smax[slot + off][lane];
      float4 s2 = ssum[slot + off][lane];
      float4 m1 = smax[slot][lane];
      float4 s1 = ssum[slot][lane];
      MAX4(m1, m2);
      ADD4(s1, s2);
      smax[slot][lane] = m1;
      ssum[slot][lane] = s1;
    }
    __syncthreads();
  }
  if (slot == 0) {
    *(float4*)&pooled[g * 256 + lane * 4]       = smax[0][lane];
    *(float4*)&pooled[g * 256 + 128 + lane * 4] = ssum[0][lane];
  }
}

// ---------------- head: mol linear+BN+relu, concat, MLP ----------------
__global__ void k_head(const float* __restrict__ pooled, const float* __restrict__ mf,
                       const float* __restrict__ Wm, const float* __restrict__ bm,
                       const float* __restrict__ gamma, const float* __restrict__ beta,
                       const float* __restrict__ W1, const float* __restrict__ b1,
                       const float* __restrict__ W2, const float* __restrict__ b2,
                       float* __restrict__ out) {
  __shared__ float z[288];
  __shared__ float z1[128];
  int g = blockIdx.x, t = threadIdx.x;  // 128 threads
  z[t] = pooled[g * 256 + t];
  z[128 + t] = pooled[g * 256 + 128 + t];
  if (t < NMH) {
    float acc = bm[t];
    for (int k = 0; k < NM; ++k) acc += mf[g * NM + k] * Wm[k * NMH + t];
    acc = acc * gamma[t] + beta[t];
    z[256 + t] = fmaxf(acc, 0.f);
  }
  __syncthreads();
  float acc = b1[t];
  for (int k = 0; k < 288; ++k) acc += z[k] * W1[k * HD + t];
  z1[t] = fmaxf(acc, 0.f);
  __syncthreads();
  if (t < NO) {
    float a2 = b2[t];
    for (int k = 0; k < HD; ++k) a2 += z1[k] * W2[k * NO + t];
    out[g * NO + t] = a2;
  }
}

extern "C" void kernel_launch(void* const* d_in, const int* in_sizes, int n_in,
                              void* d_out, int out_size, void* d_ws, size_t ws_size,
                              hipStream_t stream) {
  const float* x     = (const float*)d_in[0];
  const int*   eidx  = (const int*)d_in[1];
  const int*   batch = (const int*)d_in[2];
  const float* mf    = (const float*)d_in[3];
  const float* Ws    = (const float*)d_in[4];
  const float* bs    = (const float*)d_in[5];
  const float* Wm    = (const float*)d_in[6];
  const float* bm    = (const float*)d_in[7];
  const float* gamma = (const float*)d_in[8];
  const float* beta  = (const float*)d_in[9];
  const float* W1    = (const float*)d_in[10];
  const float* b1    = (const float*)d_in[11];
  const float* W2    = (const float*)d_in[12];
  const float* b2    = (const float*)d_in[13];
  float* out = (float*)d_out;

  const int* src = eidx;
  const int* dst = eidx + NE;

  // workspace carve-out
  char* w = (char*)d_ws;
  size_t off = 0;
  auto alloc = [&](size_t bytes) -> void* {
    void* p = w + off;
    off += (bytes + 255) & ~(size_t)255;
    return p;
  };
  float* dis    = (float*)alloc((size_t)NN * 4);
  float* h      = (float*)alloc((size_t)NN * HD * 4);
  float* xw     = (float*)alloc((size_t)NN * HD * 4);
  int* counts   = (int*)alloc((size_t)NN * 4);
  int* cur      = (int*)alloc((size_t)NN * 4);
  int* rowst    = (int*)alloc((size_t)(NN + 1) * 4);
  int* csr      = (int*)alloc((size_t)NE * 4);
  int* bsum     = (int*)alloc(256 * 4);
  int* boff     = (int*)alloc(256 * 4);
  int* goffs    = (int*)alloc((size_t)(NB + 1) * 4);
  float* pooled = (float*)alloc((size_t)NB * 256 * 4);
  (void)ws_size;

  const int SB = (NN + 255) / 256;  // 196 scan blocks

  hipMemsetAsync(counts, 0, (size_t)NN * 4, stream);
  hipMemsetAsync(cur, 0, (size_t)NN * 4, stream);

  k_hist<<<(NE + 255) / 256, 256, 0, stream>>>(dst, counts);
  k_dis<<<SB, 256, 0, stream>>>(counts, dis);
  k_scan1<<<SB, 256, 0, stream>>>(counts, rowst, bsum);
  k_scan2<<<1, 256, 0, stream>>>(bsum, boff, SB);
  k_scan3<<<SB, 256, 0, stream>>>(counts, rowst, boff);
  k_fill<<<(NE + 255) / 256, 256, 0, stream>>>(src, dst, rowst, cur, csr);

  k_goffs<<<SB, 256, 0, stream>>>(batch, goffs);

  for (int l = 0; l < NL; ++l) {
    const float* gin = (l == 0) ? x : h;
    k_gemm<<<(NN + 63) / 64, 256, 0, stream>>>(gin, Ws + (size_t)l * HD * HD, xw);
    k_agg<<<(NN + 7) / 8, 256, 0, stream>>>(xw, dis, rowst, csr, bs + (size_t)l * HD, gin, h);
  }

  k_pool<<<NB, 1024, 0, stream>>>(h, goffs, pooled);
  k_head<<<NB, 128, 0, stream>>>(pooled, mf, Wm, bm, gamma, beta, W1, b1, W2, b2, out);
}

// Round 5
// 378.734 us; speedup vs baseline: 1.3110x; 1.1495x over previous
//
#include <hip/hip_runtime.h>
#include <math.h>

// Problem constants (fixed by the reference)
static constexpr int NN  = 50000;   // nodes
static constexpr int NE  = 600000;  // edges
static constexpr int HD  = 128;     // feature dim
static constexpr int NL  = 4;       // layers
static constexpr int NB  = 256;     // graphs
static constexpr int NM  = 200;     // molecule features
static constexpr int NO  = 12;      // out features
static constexpr int NMH = 32;      // molecular head width

#define FMA4(ac, s, b) { (ac).x += (s)*(b).x; (ac).y += (s)*(b).y; (ac).z += (s)*(b).z; (ac).w += (s)*(b).w; }
#define MAX4(ac, b) { (ac).x = fmaxf((ac).x,(b).x); (ac).y = fmaxf((ac).y,(b).y); (ac).z = fmaxf((ac).z,(b).z); (ac).w = fmaxf((ac).w,(b).w); }
#define ADD4(ac, b) { (ac).x += (b).x; (ac).y += (b).y; (ac).z += (b).z; (ac).w += (b).w; }

__device__ __forceinline__ unsigned short f2bf(float f) {   // RNE float->bf16
  unsigned int u = __float_as_uint(f);
  unsigned int r = (u + 0x7fffu + ((u >> 16) & 1u)) >> 16;
  return (unsigned short)r;
}
__device__ __forceinline__ float bflo(unsigned int p) { return __uint_as_float(p << 16); }
__device__ __forceinline__ float bfhi(unsigned int p) { return __uint_as_float(p & 0xffff0000u); }

// ---------------- CSR build ----------------
__global__ void k_hist(const int* __restrict__ dst, int* __restrict__ counts) {
  int e = blockIdx.x * blockDim.x + threadIdx.x;
  if (e < NE) atomicAdd(&counts[dst[e]], 1);
}

__global__ void k_dis(const int* __restrict__ counts, float* __restrict__ dis) {
  int i = blockIdx.x * blockDim.x + threadIdx.x;
  if (i < NN) dis[i] = rsqrtf((float)(counts[i] + 1));
}

// per-block inclusive scan; writes local inclusive scan into incl, block totals into bsum
__global__ void k_scan1(const int* __restrict__ counts, int* __restrict__ incl, int* __restrict__ bsum) {
  __shared__ int s[256];
  int i = blockIdx.x * 256 + threadIdx.x;
  int v = (i < NN) ? counts[i] : 0;
  s[threadIdx.x] = v;
  __syncthreads();
  for (int off = 1; off < 256; off <<= 1) {
    int t = (threadIdx.x >= off) ? s[threadIdx.x - off] : 0;
    __syncthreads();
    s[threadIdx.x] += t;
    __syncthreads();
  }
  if (i < NN) incl[i] = s[threadIdx.x];
  if (threadIdx.x == 255) bsum[blockIdx.x] = s[255];
}

// single block: exclusive scan of up to 256 block sums
__global__ void k_scan2(const int* __restrict__ bsum, int* __restrict__ boff, int nblocks) {
  __shared__ int s[256];
  int v = (threadIdx.x < nblocks) ? bsum[threadIdx.x] : 0;
  s[threadIdx.x] = v;
  __syncthreads();
  for (int off = 1; off < 256; off <<= 1) {
    int t = (threadIdx.x >= off) ? s[threadIdx.x - off] : 0;
    __syncthreads();
    s[threadIdx.x] += t;
    __syncthreads();
  }
  boff[threadIdx.x] = s[threadIdx.x] - v;  // exclusive
}

__global__ void k_scan3(const int* __restrict__ counts, int* __restrict__ rowst, const int* __restrict__ boff) {
  int i = blockIdx.x * 256 + threadIdx.x;
  if (i < NN) {
    rowst[i] = rowst[i] - counts[i] + boff[blockIdx.x];  // exclusive global
    if (i == NN - 1) rowst[NN] = NE;
  }
}

__global__ void k_fill(const int* __restrict__ src, const int* __restrict__ dst,
                       const int* __restrict__ rowst, int* __restrict__ cur, int* __restrict__ csr) {
  int e = blockIdx.x * blockDim.x + threadIdx.x;
  if (e < NE) {
    int d = dst[e];
    int p = atomicAdd(&cur[d], 1);
    csr[rowst[d] + p] = src[e];
  }
}

// ---------------- misc ----------------
__global__ void k_goffs(const int* __restrict__ batch, int* __restrict__ goffs) {
  int i = blockIdx.x * blockDim.x + threadIdx.x;
  if (i >= NN) return;
  int b = batch[i];
  if (i == 0) {
    for (int g = 0; g <= b; ++g) goffs[g] = 0;
  } else {
    int pb = batch[i - 1];
    for (int g = pb + 1; g <= b; ++g) goffs[g] = i;
  }
  if (i == NN - 1) goffs[NB] = NN;
}

// ---------------- GEMM: C[NN,128] = A[NN,128] @ W[128,128], C stored bf16 ----------------
__launch_bounds__(256)
__global__ void k_gemm(const float* __restrict__ A, const float* __restrict__ W,
                       unsigned short* __restrict__ C) {
  __shared__ float At[16][68];   // transposed A tile, padded stride 68 (16B-aligned rows)
  __shared__ float Bt[16][128];

  const int t = threadIdx.x;
  const int tc = t & 15;         // col group: cols {tc*4..+3, 64+tc*4..+3}
  const int tr = t >> 4;         // row group 0..15: rows tr*4..tr*4+3
  const int row0 = blockIdx.x * 64 + tr * 4;
  const int lrow = t >> 2;       // 0..63 (A-load row)
  const int lc = t & 3;          // 0..3  (A-load k-chunk)
  const int grow = blockIdx.x * 64 + lrow;

  float4 acc0[4], acc1[4];
#pragma unroll
  for (int i = 0; i < 4; ++i) { acc0[i] = make_float4(0,0,0,0); acc1[i] = make_float4(0,0,0,0); }

  for (int k0 = 0; k0 < HD; k0 += 16) {
    float4 av = make_float4(0,0,0,0);
    if (grow < NN) av = *(const float4*)&A[(size_t)grow * HD + k0 + lc * 4];
    float4 bv0 = *(const float4*)&W[k0 * HD + t * 4];
    float4 bv1 = *(const float4*)&W[k0 * HD + 1024 + t * 4];

    __syncthreads();
    At[lc * 4 + 0][lrow] = av.x;
    At[lc * 4 + 1][lrow] = av.y;
    At[lc * 4 + 2][lrow] = av.z;
    At[lc * 4 + 3][lrow] = av.w;
    {
      int f0 = t * 4;           // [0,1024): rows 0..7
      int f1 = (t + 256) * 4;   // rows 8..15
      *(float4*)&Bt[f0 >> 7][f0 & 127] = bv0;
      *(float4*)&Bt[f1 >> 7][f1 & 127] = bv1;
    }
    __syncthreads();

#pragma unroll
    for (int kk = 0; kk < 16; ++kk) {
      float4 a  = *(const float4*)&At[kk][tr * 4];
      float4 b0 = *(const float4*)&Bt[kk][tc * 4];
      float4 b1 = *(const float4*)&Bt[kk][64 + tc * 4];
      FMA4(acc0[0], a.x, b0); FMA4(acc0[1], a.y, b0); FMA4(acc0[2], a.z, b0); FMA4(acc0[3], a.w, b0);
      FMA4(acc1[0], a.x, b1); FMA4(acc1[1], a.y, b1); FMA4(acc1[2], a.z, b1); FMA4(acc1[3], a.w, b1);
    }
  }

#pragma unroll
  for (int i = 0; i < 4; ++i) {
    int gr = row0 + i;
    if (gr < NN) {
      ushort4 p0 = make_ushort4(f2bf(acc0[i].x), f2bf(acc0[i].y), f2bf(acc0[i].z), f2bf(acc0[i].w));
      ushort4 p1 = make_ushort4(f2bf(acc1[i].x), f2bf(acc1[i].y), f2bf(acc1[i].z), f2bf(acc1[i].w));
      *(ushort4*)&C[(size_t)gr * HD + tc * 4]      = p0;
      *(ushort4*)&C[(size_t)gr * HD + 64 + tc * 4] = p1;
    }
  }
}

// ---------------- aggregate + bias + relu + residual ----------------
// hout[n] = relu(agg + bias) + hin[n]; xw rows are bf16 (256B)
__global__ void k_agg(const unsigned short* __restrict__ xw, const float* __restrict__ dis,
                      const int* __restrict__ rowst, const int* __restrict__ csr,
                      const float* __restrict__ bias, const float* __restrict__ hin,
                      float* __restrict__ hout) {
  int g = threadIdx.x >> 5;          // node slot 0..7
  int lane = threadIdx.x & 31;       // feature group: floats lane*4..lane*4+3
  int n = blockIdx.x * 8 + g;
  if (n >= NN) return;

  const uint2* xwb = (const uint2*)xw;   // 8B = 4 bf16 per lane; 32 lanes = 256B row

  float dn = dis[n];
  float4 acc;
  {
    uint2 p = xwb[(size_t)n * 32 + lane];
    float sl = dn * dn;
    acc.x = bflo(p.x) * sl; acc.y = bfhi(p.x) * sl;
    acc.z = bflo(p.y) * sl; acc.w = bfhi(p.y) * sl;
  }

  int s0 = rowst[n], s1 = rowst[n + 1];
  int idx = s0;
  for (; idx + 2 <= s1; idx += 2) {
    int sA = csr[idx], sB = csr[idx + 1];
    float nA = dis[sA] * dn;
    float nB = dis[sB] * dn;
    uint2 pA = xwb[(size_t)sA * 32 + lane];
    uint2 pB = xwb[(size_t)sB * 32 + lane];
    acc.x += nA * bflo(pA.x); acc.y += nA * bfhi(pA.x);
    acc.z += nA * bflo(pA.y); acc.w += nA * bfhi(pA.y);
    acc.x += nB * bflo(pB.x); acc.y += nB * bfhi(pB.x);
    acc.z += nB * bflo(pB.y); acc.w += nB * bfhi(pB.y);
  }
  if (idx < s1) {
    int sA = csr[idx];
    float nA = dis[sA] * dn;
    uint2 pA = xwb[(size_t)sA * 32 + lane];
    acc.x += nA * bflo(pA.x); acc.y += nA * bfhi(pA.x);
    acc.z += nA * bflo(pA.y); acc.w += nA * bfhi(pA.y);
  }

  float4 b4 = *(const float4*)&bias[lane * 4];
  float4 hv = *(const float4*)&hin[(size_t)n * HD + lane * 4];
  float4 out;
  out.x = fmaxf(acc.x + b4.x, 0.f) + hv.x;
  out.y = fmaxf(acc.y + b4.y, 0.f) + hv.y;
  out.z = fmaxf(acc.z + b4.z, 0.f) + hv.z;
  out.w = fmaxf(acc.w + b4.w, 0.f) + hv.w;
  *(float4*)&hout[(size_t)n * HD + lane * 4] = out;
}

// ---------------- pooling: per-graph max & sum (parallel over 32 node slots) ----------------
__launch_bounds__(1024)
__global__ void k_pool(const float* __restrict__ h, const int* __restrict__ goffs,
                       float* __restrict__ pooled) {
  __shared__ float4 smax[32][32];   // [slot][lane]
  __shared__ float4 ssum[32][32];
  int g = blockIdx.x;
  int slot = threadIdx.x >> 5;      // 0..31: node slot
  int lane = threadIdx.x & 31;      // feature group: floats lane*4..+3
  int a = goffs[g], bnd = goffs[g + 1];

  float4 mx = make_float4(-INFINITY, -INFINITY, -INFINITY, -INFINITY);
  float4 sm = make_float4(0.f, 0.f, 0.f, 0.f);
  for (int i = a + slot; i < bnd; i += 32) {
    float4 v = *(const float4*)&h[(size_t)i * HD + lane * 4];
    MAX4(mx, v);
    ADD4(sm, v);
  }
  smax[slot][lane] = mx;
  ssum[slot][lane] = sm;
  __syncthreads();
#pragma unroll
  for (int off = 16; off >= 1; off >>= 1) {
    if (slot < off) {
      float4 m2 = smax[slot + off][lane];
      float4 s2 = ssum[slot + off][lane];
      float4 m1 = smax[slot][lane];
      float4 s1 = ssum[slot][lane];
      MAX4(m1, m2);
      ADD4(s1, s2);
      smax[slot][lane] = m1;
      ssum[slot][lane] = s1;
    }
    __syncthreads();
  }
  if (slot == 0) {
    *(float4*)&pooled[g * 256 + lane * 4]       = smax[0][lane];
    *(float4*)&pooled[g * 256 + 128 + lane * 4] = ssum[0][lane];
  }
}

// ---------------- head: mol linear+BN+relu, concat, MLP ----------------
__global__ void k_head(const float* __restrict__ pooled, const float* __restrict__ mf,
                       const float* __restrict__ Wm, const float* __restrict__ bm,
                       const float* __restrict__ gamma, const float* __restrict__ beta,
                       const float* __restrict__ W1, const float* __restrict__ b1,
                       const float* __restrict__ W2, const float* __restrict__ b2,
                       float* __restrict__ out) {
  __shared__ float z[288];
  __shared__ float z1[128];
  int g = blockIdx.x, t = threadIdx.x;  // 128 threads
  z[t] = pooled[g * 256 + t];
  z[128 + t] = pooled[g * 256 + 128 + t];
  if (t < NMH) {
    float acc = bm[t];
    for (int k = 0; k < NM; ++k) acc += mf[g * NM + k] * Wm[k * NMH + t];
    acc = acc * gamma[t] + beta[t];
    z[256 + t] = fmaxf(acc, 0.f);
  }
  __syncthreads();
  float acc = b1[t];
  for (int k = 0; k < 288; ++k) acc += z[k] * W1[k * HD + t];
  z1[t] = fmaxf(acc, 0.f);
  __syncthreads();
  if (t < NO) {
    float a2 = b2[t];
    for (int k = 0; k < HD; ++k) a2 += z1[k] * W2[k * NO + t];
    out[g * NO + t] = a2;
  }
}

extern "C" void kernel_launch(void* const* d_in, const int* in_sizes, int n_in,
                              void* d_out, int out_size, void* d_ws, size_t ws_size,
                              hipStream_t stream) {
  const float* x     = (const float*)d_in[0];
  const int*   eidx  = (const int*)d_in[1];
  const int*   batch = (const int*)d_in[2];
  const float* mf    = (const float*)d_in[3];
  const float* Ws    = (const float*)d_in[4];
  const float* bs    = (const float*)d_in[5];
  const float* Wm    = (const float*)d_in[6];
  const float* bm    = (const float*)d_in[7];
  const float* gamma = (const float*)d_in[8];
  const float* beta  = (const float*)d_in[9];
  const float* W1    = (const float*)d_in[10];
  const float* b1    = (const float*)d_in[11];
  const float* W2    = (const float*)d_in[12];
  const float* b2    = (const float*)d_in[13];
  float* out = (float*)d_out;

  const int* src = eidx;
  const int* dst = eidx + NE;

  // workspace carve-out
  char* w = (char*)d_ws;
  size_t off = 0;
  auto alloc = [&](size_t bytes) -> void* {
    void* p = w + off;
    off += (bytes + 255) & ~(size_t)255;
    return p;
  };
  float* dis    = (float*)alloc((size_t)NN * 4);
  float* h      = (float*)alloc((size_t)NN * HD * 4);
  unsigned short* xw = (unsigned short*)alloc((size_t)NN * HD * 2);  // bf16
  int* counts   = (int*)alloc((size_t)NN * 4);
  int* cur      = (int*)alloc((size_t)NN * 4);
  int* rowst    = (int*)alloc((size_t)(NN + 1) * 4);
  int* csr      = (int*)alloc((size_t)NE * 4);
  int* bsum     = (int*)alloc(256 * 4);
  int* boff     = (int*)alloc(256 * 4);
  int* goffs    = (int*)alloc((size_t)(NB + 1) * 4);
  float* pooled = (float*)alloc((size_t)NB * 256 * 4);
  (void)ws_size;

  const int SB = (NN + 255) / 256;  // 196 scan blocks

  hipMemsetAsync(counts, 0, (size_t)NN * 4, stream);
  hipMemsetAsync(cur, 0, (size_t)NN * 4, stream);

  k_hist<<<(NE + 255) / 256, 256, 0, stream>>>(dst, counts);
  k_dis<<<SB, 256, 0, stream>>>(counts, dis);
  k_scan1<<<SB, 256, 0, stream>>>(counts, rowst, bsum);
  k_scan2<<<1, 256, 0, stream>>>(bsum, boff, SB);
  k_scan3<<<SB, 256, 0, stream>>>(counts, rowst, boff);
  k_fill<<<(NE + 255) / 256, 256, 0, stream>>>(src, dst, rowst, cur, csr);

  k_goffs<<<SB, 256, 0, stream>>>(batch, goffs);

  for (int l = 0; l < NL; ++l) {
    const float* gin = (l == 0) ? x : h;
    k_gemm<<<(NN + 63) / 64, 256, 0, stream>>>(gin, Ws + (size_t)l * HD * HD, xw);
    k_agg<<<(NN + 7) / 8, 256, 0, stream>>>(xw, dis, rowst, csr, bs + (size_t)l * HD, gin, h);
  }

  k_pool<<<NB, 1024, 0, stream>>>(h, goffs, pooled);
  k_head<<<NB, 128, 0, stream>>>(pooled, mf, Wm, bm, gamma, beta, W1, b1, W2, b2, out);
}

// Round 6
// 315.486 us; speedup vs baseline: 1.5739x; 1.2005x over previous
//
#include <hip/hip_runtime.h>
#include <math.h>

// Problem constants (fixed by the reference)
static constexpr int NN  = 50000;   // nodes
static constexpr int NE  = 600000;  // edges
static constexpr int HD  = 128;     // feature dim
static constexpr int NL  = 4;       // layers
static constexpr int NB  = 256;     // graphs
static constexpr int NM  = 200;     // molecule features
static constexpr int NO  = 12;      // out features
static constexpr int NMH = 32;      // molecular head width

#define MAX4(ac, b) { (ac).x = fmaxf((ac).x,(b).x); (ac).y = fmaxf((ac).y,(b).y); (ac).z = fmaxf((ac).z,(b).z); (ac).w = fmaxf((ac).w,(b).w); }
#define ADD4(ac, b) { (ac).x += (b).x; (ac).y += (b).y; (ac).z += (b).z; (ac).w += (b).w; }

typedef short bfx8 __attribute__((ext_vector_type(8)));   // 8 bf16 in 4 VGPRs
typedef float f32x4 __attribute__((ext_vector_type(4)));  // MFMA accumulator

__device__ __forceinline__ unsigned short f2bf(float f) {   // RNE float->bf16
  unsigned int u = __float_as_uint(f);
  unsigned int r = (u + 0x7fffu + ((u >> 16) & 1u)) >> 16;
  return (unsigned short)r;
}
__device__ __forceinline__ float bflo(unsigned int p) { return __uint_as_float(p << 16); }
__device__ __forceinline__ float bfhi(unsigned int p) { return __uint_as_float(p & 0xffff0000u); }

// ---------------- CSR build ----------------
__global__ void k_hist(const int* __restrict__ dst, int* __restrict__ counts) {
  int e = blockIdx.x * blockDim.x + threadIdx.x;
  if (e < NE) atomicAdd(&counts[dst[e]], 1);
}

__global__ void k_dis(const int* __restrict__ counts, float* __restrict__ dis) {
  int i = blockIdx.x * blockDim.x + threadIdx.x;
  if (i < NN) dis[i] = rsqrtf((float)(counts[i] + 1));
}

__global__ void k_scan1(const int* __restrict__ counts, int* __restrict__ incl, int* __restrict__ bsum) {
  __shared__ int s[256];
  int i = blockIdx.x * 256 + threadIdx.x;
  int v = (i < NN) ? counts[i] : 0;
  s[threadIdx.x] = v;
  __syncthreads();
  for (int off = 1; off < 256; off <<= 1) {
    int t = (threadIdx.x >= off) ? s[threadIdx.x - off] : 0;
    __syncthreads();
    s[threadIdx.x] += t;
    __syncthreads();
  }
  if (i < NN) incl[i] = s[threadIdx.x];
  if (threadIdx.x == 255) bsum[blockIdx.x] = s[255];
}

__global__ void k_scan2(const int* __restrict__ bsum, int* __restrict__ boff, int nblocks) {
  __shared__ int s[256];
  int v = (threadIdx.x < nblocks) ? bsum[threadIdx.x] : 0;
  s[threadIdx.x] = v;
  __syncthreads();
  for (int off = 1; off < 256; off <<= 1) {
    int t = (threadIdx.x >= off) ? s[threadIdx.x - off] : 0;
    __syncthreads();
    s[threadIdx.x] += t;
    __syncthreads();
  }
  boff[threadIdx.x] = s[threadIdx.x] - v;  // exclusive
}

__global__ void k_scan3(const int* __restrict__ counts, int* __restrict__ rowst, const int* __restrict__ boff) {
  int i = blockIdx.x * 256 + threadIdx.x;
  if (i < NN) {
    rowst[i] = rowst[i] - counts[i] + boff[blockIdx.x];  // exclusive global
    if (i == NN - 1) rowst[NN] = NE;
  }
}

__global__ void k_fill(const int* __restrict__ src, const int* __restrict__ dst,
                       const int* __restrict__ rowst, int* __restrict__ cur, int* __restrict__ csr) {
  int e = blockIdx.x * blockDim.x + threadIdx.x;
  if (e < NE) {
    int d = dst[e];
    int p = atomicAdd(&cur[d], 1);
    csr[rowst[d] + p] = src[e];
  }
}

// ---------------- misc ----------------
__global__ void k_goffs(const int* __restrict__ batch, int* __restrict__ goffs) {
  int i = blockIdx.x * blockDim.x + threadIdx.x;
  if (i >= NN) return;
  int b = batch[i];
  if (i == 0) {
    for (int g = 0; g <= b; ++g) goffs[g] = 0;
  } else {
    int pb = batch[i - 1];
    for (int g = pb + 1; g <= b; ++g) goffs[g] = i;
  }
  if (i == NN - 1) goffs[NB] = NN;
}

// fp32 -> bf16 conversion (4 elems/thread)
__global__ void k_tobf(const float4* __restrict__ in, ushort4* __restrict__ outb, int n4) {
  int i = blockIdx.x * blockDim.x + threadIdx.x;
  if (i < n4) {
    float4 v = in[i];
    outb[i] = make_ushort4(f2bf(v.x), f2bf(v.y), f2bf(v.z), f2bf(v.w));
  }
}

// Ws[l][k][n] -> wT[l][n][k] bf16
__global__ void k_wT(const float* __restrict__ Ws, unsigned short* __restrict__ wT) {
  int i = blockIdx.x * blockDim.x + threadIdx.x;
  if (i < NL * HD * HD) {
    int l = i >> 14, rem = i & 16383, n = rem >> 7, k = rem & 127;
    wT[i] = f2bf(Ws[l * 16384 + k * 128 + n]);
  }
}

// ---------------- MFMA GEMM: C[NN,128] = A[NN,128] @ W, A/C bf16, W as WT[n][k] bf16 ----------------
// Per wave: 32 rows x 128 cols. Block 256 thr = 4 waves = 128 rows. No LDS.
__launch_bounds__(256)
__global__ void k_gemm_mfma(const unsigned short* __restrict__ A,
                            const unsigned short* __restrict__ WT,
                            unsigned short* __restrict__ C) {
  const int wave = threadIdx.x >> 6;
  const int lane = threadIdx.x & 63;
  const int m_base = blockIdx.x * 128 + wave * 32;
  const int lr = lane & 15;       // A row-in-frag / B col-in-frag
  const int kg = lane >> 4;       // k-subgroup: 8 contiguous k elems

  f32x4 acc[2][8];
#pragma unroll
  for (int mi = 0; mi < 2; ++mi)
#pragma unroll
    for (int nj = 0; nj < 8; ++nj) acc[mi][nj] = (f32x4){0.f, 0.f, 0.f, 0.f};

  int ra0 = m_base + lr;       if (ra0 > NN - 1) ra0 = NN - 1;
  int ra1 = m_base + 16 + lr;  if (ra1 > NN - 1) ra1 = NN - 1;

#pragma unroll
  for (int kb = 0; kb < 4; ++kb) {
    const int k0 = kb * 32 + kg * 8;
    bfx8 a0 = *(const bfx8*)&A[(size_t)ra0 * HD + k0];
    bfx8 a1 = *(const bfx8*)&A[(size_t)ra1 * HD + k0];
#pragma unroll
    for (int nj = 0; nj < 8; ++nj) {
      bfx8 b = *(const bfx8*)&WT[(nj * 16 + lr) * HD + k0];
      acc[0][nj] = __builtin_amdgcn_mfma_f32_16x16x32_bf16(a0, b, acc[0][nj], 0, 0, 0);
      acc[1][nj] = __builtin_amdgcn_mfma_f32_16x16x32_bf16(a1, b, acc[1][nj], 0, 0, 0);
    }
  }

  // C/D layout: col = lane&15, row = (lane>>4)*4 + reg   [m89 verified]
  const int col = lane & 15;
  const int rbase = (lane >> 4) * 4;
#pragma unroll
  for (int mi = 0; mi < 2; ++mi) {
#pragma unroll
    for (int r = 0; r < 4; ++r) {
      int row = m_base + mi * 16 + rbase + r;
      if (row < NN) {
#pragma unroll
        for (int nj = 0; nj < 8; ++nj) {
          C[(size_t)row * HD + nj * 16 + col] = f2bf(acc[mi][nj][r]);
        }
      }
    }
  }
}

// ---------------- aggregate + bias + relu + residual ----------------
// hout[n] = relu(agg + bias) + hin[n]; also writes bf16 copy for next layer's GEMM
__global__ void k_agg(const unsigned short* __restrict__ xw, const float* __restrict__ dis,
                      const int* __restrict__ rowst, const int* __restrict__ csr,
                      const float* __restrict__ bias, const float* __restrict__ hin,
                      float* __restrict__ hout, unsigned short* __restrict__ houtb) {
  int g = threadIdx.x >> 5;          // node slot 0..7
  int lane = threadIdx.x & 31;       // feature group: floats lane*4..lane*4+3
  int n = blockIdx.x * 8 + g;
  if (n >= NN) return;

  const uint2* xwb = (const uint2*)xw;   // 8B = 4 bf16 per lane

  float dn = dis[n];
  float4 acc;
  {
    uint2 p = xwb[(size_t)n * 32 + lane];
    float sl = dn * dn;
    acc.x = bflo(p.x) * sl; acc.y = bfhi(p.x) * sl;
    acc.z = bflo(p.y) * sl; acc.w = bfhi(p.y) * sl;
  }

  int s0 = rowst[n], s1 = rowst[n + 1];
  int idx = s0;
  for (; idx + 2 <= s1; idx += 2) {
    int sA = csr[idx], sB = csr[idx + 1];
    float nA = dis[sA] * dn;
    float nB = dis[sB] * dn;
    uint2 pA = xwb[(size_t)sA * 32 + lane];
    uint2 pB = xwb[(size_t)sB * 32 + lane];
    acc.x += nA * bflo(pA.x); acc.y += nA * bfhi(pA.x);
    acc.z += nA * bflo(pA.y); acc.w += nA * bfhi(pA.y);
    acc.x += nB * bflo(pB.x); acc.y += nB * bfhi(pB.x);
    acc.z += nB * bflo(pB.y); acc.w += nB * bfhi(pB.y);
  }
  if (idx < s1) {
    int sA = csr[idx];
    float nA = dis[sA] * dn;
    uint2 pA = xwb[(size_t)sA * 32 + lane];
    acc.x += nA * bflo(pA.x); acc.y += nA * bfhi(pA.x);
    acc.z += nA * bflo(pA.y); acc.w += nA * bfhi(pA.y);
  }

  float4 b4 = *(const float4*)&bias[lane * 4];
  float4 hv = *(const float4*)&hin[(size_t)n * HD + lane * 4];
  float4 out;
  out.x = fmaxf(acc.x + b4.x, 0.f) + hv.x;
  out.y = fmaxf(acc.y + b4.y, 0.f) + hv.y;
  out.z = fmaxf(acc.z + b4.z, 0.f) + hv.z;
  out.w = fmaxf(acc.w + b4.w, 0.f) + hv.w;
  *(float4*)&hout[(size_t)n * HD + lane * 4] = out;
  *(ushort4*)&houtb[(size_t)n * HD + lane * 4] =
      make_ushort4(f2bf(out.x), f2bf(out.y), f2bf(out.z), f2bf(out.w));
}

// ---------------- pooling: per-graph max & sum (parallel over 32 node slots) ----------------
__launch_bounds__(1024)
__global__ void k_pool(const float* __restrict__ h, const int* __restrict__ goffs,
                       float* __restrict__ pooled) {
  __shared__ float4 smax[32][32];   // [slot][lane]
  __shared__ float4 ssum[32][32];
  int g = blockIdx.x;
  int slot = threadIdx.x >> 5;
  int lane = threadIdx.x & 31;
  int a = goffs[g], bnd = goffs[g + 1];

  float4 mx = make_float4(-INFINITY, -INFINITY, -INFINITY, -INFINITY);
  float4 sm = make_float4(0.f, 0.f, 0.f, 0.f);
  for (int i = a + slot; i < bnd; i += 32) {
    float4 v = *(const float4*)&h[(size_t)i * HD + lane * 4];
    MAX4(mx, v);
    ADD4(sm, v);
  }
  smax[slot][lane] = mx;
  ssum[slot][lane] = sm;
  __syncthreads();
#pragma unroll
  for (int off = 16; off >= 1; off >>= 1) {
    if (slot < off) {
      float4 m2 = smax[slot + off][lane];
      float4 s2 = ssum[slot + off][lane];
      float4 m1 = smax[slot][lane];
      float4 s1 = ssum[slot][lane];
      MAX4(m1, m2);
      ADD4(s1, s2);
      smax[slot][lane] = m1;
      ssum[slot][lane] = s1;
    }
    __syncthreads();
  }
  if (slot == 0) {
    *(float4*)&pooled[g * 256 + lane * 4]       = smax[0][lane];
    *(float4*)&pooled[g * 256 + 128 + lane * 4] = ssum[0][lane];
  }
}

// ---------------- head: mol linear+BN+relu, concat, MLP ----------------
__global__ void k_head(const float* __restrict__ pooled, const float* __restrict__ mf,
                       const float* __restrict__ Wm, const float* __restrict__ bm,
                       const float* __restrict__ gamma, const float* __restrict__ beta,
                       const float* __restrict__ W1, const float* __restrict__ b1,
                       const float* __restrict__ W2, const float* __restrict__ b2,
                       float* __restrict__ out) {
  __shared__ float z[288];
  __shared__ float z1[128];
  int g = blockIdx.x, t = threadIdx.x;  // 128 threads
  z[t] = pooled[g * 256 + t];
  z[128 + t] = pooled[g * 256 + 128 + t];
  if (t < NMH) {
    float acc = bm[t];
    for (int k = 0; k < NM; ++k) acc += mf[g * NM + k] * Wm[k * NMH + t];
    acc = acc * gamma[t] + beta[t];
    z[256 + t] = fmaxf(acc, 0.f);
  }
  __syncthreads();
  float acc = b1[t];
  for (int k = 0; k < 288; ++k) acc += z[k] * W1[k * HD + t];
  z1[t] = fmaxf(acc, 0.f);
  __syncthreads();
  if (t < NO) {
    float a2 = b2[t];
    for (int k = 0; k < HD; ++k) a2 += z1[k] * W2[k * NO + t];
    out[g * NO + t] = a2;
  }
}

extern "C" void kernel_launch(void* const* d_in, const int* in_sizes, int n_in,
                              void* d_out, int out_size, void* d_ws, size_t ws_size,
                              hipStream_t stream) {
  const float* x     = (const float*)d_in[0];
  const int*   eidx  = (const int*)d_in[1];
  const int*   batch = (const int*)d_in[2];
  const float* mf    = (const float*)d_in[3];
  const float* Ws    = (const float*)d_in[4];
  const float* bs    = (const float*)d_in[5];
  const float* Wm    = (const float*)d_in[6];
  const float* bm    = (const float*)d_in[7];
  const float* gamma = (const float*)d_in[8];
  const float* beta  = (const float*)d_in[9];
  const float* W1    = (const float*)d_in[10];
  const float* b1    = (const float*)d_in[11];
  const float* W2    = (const float*)d_in[12];
  const float* b2    = (const float*)d_in[13];
  float* out = (float*)d_out;

  const int* src = eidx;
  const int* dst = eidx + NE;

  // workspace carve-out
  char* w = (char*)d_ws;
  size_t off = 0;
  auto alloc = [&](size_t bytes) -> void* {
    void* p = w + off;
    off += (bytes + 255) & ~(size_t)255;
    return p;
  };
  float* dis    = (float*)alloc((size_t)NN * 4);
  float* h      = (float*)alloc((size_t)NN * HD * 4);
  unsigned short* xw  = (unsigned short*)alloc((size_t)NN * HD * 2);  // bf16 GEMM out
  unsigned short* xbf = (unsigned short*)alloc((size_t)NN * HD * 2);  // bf16 copy of x
  unsigned short* hbf = (unsigned short*)alloc((size_t)NN * HD * 2);  // bf16 copy of h
  unsigned short* wT  = (unsigned short*)alloc((size_t)NL * HD * HD * 2);
  int* counts   = (int*)alloc((size_t)NN * 4);
  int* cur      = (int*)alloc((size_t)NN * 4);
  int* rowst    = (int*)alloc((size_t)(NN + 1) * 4);
  int* csr      = (int*)alloc((size_t)NE * 4);
  int* bsum     = (int*)alloc(256 * 4);
  int* boff     = (int*)alloc(256 * 4);
  int* goffs    = (int*)alloc((size_t)(NB + 1) * 4);
  float* pooled = (float*)alloc((size_t)NB * 256 * 4);
  (void)ws_size;

  const int SB = (NN + 255) / 256;

  hipMemsetAsync(counts, 0, (size_t)NN * 4, stream);
  hipMemsetAsync(cur, 0, (size_t)NN * 4, stream);

  k_hist<<<(NE + 255) / 256, 256, 0, stream>>>(dst, counts);
  k_dis<<<SB, 256, 0, stream>>>(counts, dis);
  k_scan1<<<SB, 256, 0, stream>>>(counts, rowst, bsum);
  k_scan2<<<1, 256, 0, stream>>>(bsum, boff, SB);
  k_scan3<<<SB, 256, 0, stream>>>(counts, rowst, boff);
  k_fill<<<(NE + 255) / 256, 256, 0, stream>>>(src, dst, rowst, cur, csr);

  k_goffs<<<SB, 256, 0, stream>>>(batch, goffs);
  k_tobf<<<((NN * HD / 4) + 255) / 256, 256, 0, stream>>>((const float4*)x, (ushort4*)xbf, NN * HD / 4);
  k_wT<<<(NL * HD * HD + 255) / 256, 256, 0, stream>>>(Ws, wT);

  for (int l = 0; l < NL; ++l) {
    const unsigned short* gin_bf = (l == 0) ? xbf : hbf;
    const float* resid = (l == 0) ? x : h;
    k_gemm_mfma<<<(NN + 127) / 128, 256, 0, stream>>>(gin_bf, wT + (size_t)l * HD * HD, xw);
    k_agg<<<(NN + 7) / 8, 256, 0, stream>>>(xw, dis, rowst, csr, bs + (size_t)l * HD, resid, h, hbf);
  }

  k_pool<<<NB, 1024, 0, stream>>>(h, goffs, pooled);
  k_head<<<NB, 128, 0, stream>>>(pooled, mf, Wm, bm, gamma, beta, W1, b1, W2, b2, out);
}

// Round 7
// 291.534 us; speedup vs baseline: 1.7032x; 1.0822x over previous
//
#include <hip/hip_runtime.h>
#include <math.h>

// Problem constants (fixed by the reference)
static constexpr int NN  = 50000;   // nodes
static constexpr int NE  = 600000;  // edges
static constexpr int HD  = 128;     // feature dim
static constexpr int NL  = 4;       // layers
static constexpr int NB  = 256;     // graphs
static constexpr int NM  = 200;     // molecule features
static constexpr int NO  = 12;      // out features
static constexpr int NMH = 32;      // molecular head width

#define MAX4(ac, b) { (ac).x = fmaxf((ac).x,(b).x); (ac).y = fmaxf((ac).y,(b).y); (ac).z = fmaxf((ac).z,(b).z); (ac).w = fmaxf((ac).w,(b).w); }
#define ADD4(ac, b) { (ac).x += (b).x; (ac).y += (b).y; (ac).z += (b).z; (ac).w += (b).w; }

typedef short bfx8 __attribute__((ext_vector_type(8)));   // 8 bf16 in 4 VGPRs
typedef float f32x4 __attribute__((ext_vector_type(4)));  // MFMA accumulator

__device__ __forceinline__ unsigned short f2bf(float f) {   // RNE float->bf16
  unsigned int u = __float_as_uint(f);
  unsigned int r = (u + 0x7fffu + ((u >> 16) & 1u)) >> 16;
  return (unsigned short)r;
}
__device__ __forceinline__ float bflo(unsigned int p) { return __uint_as_float(p << 16); }
__device__ __forceinline__ float bfhi(unsigned int p) { return __uint_as_float(p & 0xffff0000u); }

// ---------------- CSR build ----------------
__global__ void k_hist(const int* __restrict__ dst, int* __restrict__ counts) {
  int e = blockIdx.x * blockDim.x + threadIdx.x;
  if (e < NE) atomicAdd(&counts[dst[e]], 1);
}

// scan1 also computes dis = rsqrt(deg+1)
__global__ void k_scan1(const int* __restrict__ counts, int* __restrict__ incl,
                        int* __restrict__ bsum, float* __restrict__ dis) {
  __shared__ int s[256];
  int i = blockIdx.x * 256 + threadIdx.x;
  int v = (i < NN) ? counts[i] : 0;
  if (i < NN) dis[i] = rsqrtf((float)(v + 1));
  s[threadIdx.x] = v;
  __syncthreads();
  for (int off = 1; off < 256; off <<= 1) {
    int t = (threadIdx.x >= off) ? s[threadIdx.x - off] : 0;
    __syncthreads();
    s[threadIdx.x] += t;
    __syncthreads();
  }
  if (i < NN) incl[i] = s[threadIdx.x];
  if (threadIdx.x == 255) bsum[blockIdx.x] = s[255];
}

__global__ void k_scan2(const int* __restrict__ bsum, int* __restrict__ boff, int nblocks) {
  __shared__ int s[256];
  int v = (threadIdx.x < nblocks) ? bsum[threadIdx.x] : 0;
  s[threadIdx.x] = v;
  __syncthreads();
  for (int off = 1; off < 256; off <<= 1) {
    int t = (threadIdx.x >= off) ? s[threadIdx.x - off] : 0;
    __syncthreads();
    s[threadIdx.x] += t;
    __syncthreads();
  }
  boff[threadIdx.x] = s[threadIdx.x] - v;  // exclusive
}

__global__ void k_scan3(const int* __restrict__ counts, int* __restrict__ rowst, const int* __restrict__ boff) {
  int i = blockIdx.x * 256 + threadIdx.x;
  if (i < NN) {
    rowst[i] = rowst[i] - counts[i] + boff[blockIdx.x];  // exclusive global
    if (i == NN - 1) rowst[NN] = NE;
  }
}

// csr entry = (src, bits(dis[src])) — kills the dependent dis[] gather in k_agg
__global__ void k_fill(const int* __restrict__ src, const int* __restrict__ dst,
                       const int* __restrict__ rowst, const float* __restrict__ dis,
                       int* __restrict__ cur, uint2* __restrict__ csr) {
  int e = blockIdx.x * blockDim.x + threadIdx.x;
  if (e < NE) {
    int d = dst[e];
    int s = src[e];
    int p = atomicAdd(&cur[d], 1);
    csr[rowst[d] + p] = make_uint2((unsigned)s, __float_as_uint(dis[s]));
  }
}

// ---------------- misc ----------------
__global__ void k_goffs(const int* __restrict__ batch, int* __restrict__ goffs) {
  int i = blockIdx.x * blockDim.x + threadIdx.x;
  if (i >= NN) return;
  int b = batch[i];
  if (i == 0) {
    for (int g = 0; g <= b; ++g) goffs[g] = 0;
  } else {
    int pb = batch[i - 1];
    for (int g = pb + 1; g <= b; ++g) goffs[g] = i;
  }
  if (i == NN - 1) goffs[NB] = NN;
}

// fp32 -> bf16 conversion (4 elems/thread)
__global__ void k_tobf(const float4* __restrict__ in, ushort4* __restrict__ outb, int n4) {
  int i = blockIdx.x * blockDim.x + threadIdx.x;
  if (i < n4) {
    float4 v = in[i];
    outb[i] = make_ushort4(f2bf(v.x), f2bf(v.y), f2bf(v.z), f2bf(v.w));
  }
}

// Ws[l][k][n] -> wT[l][n][k] bf16
__global__ void k_wT(const float* __restrict__ Ws, unsigned short* __restrict__ wT) {
  int i = blockIdx.x * blockDim.x + threadIdx.x;
  if (i < NL * HD * HD) {
    int l = i >> 14, rem = i & 16383, n = rem >> 7, k = rem & 127;
    wT[i] = f2bf(Ws[l * 16384 + k * 128 + n]);
  }
}

// ---------------- MFMA GEMM: C[NN,128] = A[NN,128] @ W, A/C bf16, W as WT[n][k] bf16 ----------------
__launch_bounds__(256)
__global__ void k_gemm_mfma(const unsigned short* __restrict__ A,
                            const unsigned short* __restrict__ WT,
                            unsigned short* __restrict__ C) {
  const int wave = threadIdx.x >> 6;
  const int lane = threadIdx.x & 63;
  const int m_base = blockIdx.x * 128 + wave * 32;
  const int lr = lane & 15;       // A row-in-frag / B col-in-frag
  const int kg = lane >> 4;       // k-subgroup: 8 contiguous k elems

  f32x4 acc[2][8];
#pragma unroll
  for (int mi = 0; mi < 2; ++mi)
#pragma unroll
    for (int nj = 0; nj < 8; ++nj) acc[mi][nj] = (f32x4){0.f, 0.f, 0.f, 0.f};

  int ra0 = m_base + lr;       if (ra0 > NN - 1) ra0 = NN - 1;
  int ra1 = m_base + 16 + lr;  if (ra1 > NN - 1) ra1 = NN - 1;

#pragma unroll
  for (int kb = 0; kb < 4; ++kb) {
    const int k0 = kb * 32 + kg * 8;
    bfx8 a0 = *(const bfx8*)&A[(size_t)ra0 * HD + k0];
    bfx8 a1 = *(const bfx8*)&A[(size_t)ra1 * HD + k0];
#pragma unroll
    for (int nj = 0; nj < 8; ++nj) {
      bfx8 b = *(const bfx8*)&WT[(nj * 16 + lr) * HD + k0];
      acc[0][nj] = __builtin_amdgcn_mfma_f32_16x16x32_bf16(a0, b, acc[0][nj], 0, 0, 0);
      acc[1][nj] = __builtin_amdgcn_mfma_f32_16x16x32_bf16(a1, b, acc[1][nj], 0, 0, 0);
    }
  }

  // C/D layout: col = lane&15, row = (lane>>4)*4 + reg   [m89 verified]
  const int col = lane & 15;
  const int rbase = (lane >> 4) * 4;
#pragma unroll
  for (int mi = 0; mi < 2; ++mi) {
#pragma unroll
    for (int r = 0; r < 4; ++r) {
      int row = m_base + mi * 16 + rbase + r;
      if (row < NN) {
#pragma unroll
        for (int nj = 0; nj < 8; ++nj) {
          C[(size_t)row * HD + nj * 16 + col] = f2bf(acc[mi][nj][r]);
        }
      }
    }
  }
}

// ---------------- aggregate + bias + relu + residual (all bf16 state) ----------------
// houtb[n] = bf16( relu(agg + bias) + hinb[n] ); may alias hinb (row n read before write, same thread)
__global__ void k_agg(const unsigned short* __restrict__ xw, const float* __restrict__ dis,
                      const int* __restrict__ rowst, const uint2* __restrict__ csr,
                      const float* __restrict__ bias, const unsigned short* __restrict__ hinb,
                      unsigned short* __restrict__ houtb) {
  int g = threadIdx.x >> 5;          // node slot 0..7
  int lane = threadIdx.x & 31;       // feature group: floats lane*4..lane*4+3
  int n = blockIdx.x * 8 + g;
  if (n >= NN) return;

  const uint2* xwb = (const uint2*)xw;   // 8B = 4 bf16 per lane

  float dn = dis[n];
  float4 acc;
  {
    uint2 p = xwb[(size_t)n * 32 + lane];
    float sl = dn * dn;
    acc.x = bflo(p.x) * sl; acc.y = bfhi(p.x) * sl;
    acc.z = bflo(p.y) * sl; acc.w = bfhi(p.y) * sl;
  }

  int s0 = rowst[n], s1 = rowst[n + 1];
  int idx = s0;
  for (; idx + 4 <= s1; idx += 4) {
    uint2 eA = csr[idx], eB = csr[idx + 1], eC = csr[idx + 2], eD = csr[idx + 3];
    uint2 pA = xwb[(size_t)eA.x * 32 + lane];
    uint2 pB = xwb[(size_t)eB.x * 32 + lane];
    uint2 pC = xwb[(size_t)eC.x * 32 + lane];
    uint2 pD = xwb[(size_t)eD.x * 32 + lane];
    float nA = __uint_as_float(eA.y) * dn;
    float nB = __uint_as_float(eB.y) * dn;
    float nC = __uint_as_float(eC.y) * dn;
    float nD = __uint_as_float(eD.y) * dn;
    acc.x += nA * bflo(pA.x); acc.y += nA * bfhi(pA.x);
    acc.z += nA * bflo(pA.y); acc.w += nA * bfhi(pA.y);
    acc.x += nB * bflo(pB.x); acc.y += nB * bfhi(pB.x);
    acc.z += nB * bflo(pB.y); acc.w += nB * bfhi(pB.y);
    acc.x += nC * bflo(pC.x); acc.y += nC * bfhi(pC.x);
    acc.z += nC * bflo(pC.y); acc.w += nC * bfhi(pC.y);
    acc.x += nD * bflo(pD.x); acc.y += nD * bfhi(pD.x);
    acc.z += nD * bflo(pD.y); acc.w += nD * bfhi(pD.y);
  }
  for (; idx < s1; ++idx) {
    uint2 eA = csr[idx];
    uint2 pA = xwb[(size_t)eA.x * 32 + lane];
    float nA = __uint_as_float(eA.y) * dn;
    acc.x += nA * bflo(pA.x); acc.y += nA * bfhi(pA.x);
    acc.z += nA * bflo(pA.y); acc.w += nA * bfhi(pA.y);
  }

  float4 b4 = *(const float4*)&bias[lane * 4];
  uint2 hp = ((const uint2*)hinb)[(size_t)n * 32 + lane];
  float4 outv;
  outv.x = fmaxf(acc.x + b4.x, 0.f) + bflo(hp.x);
  outv.y = fmaxf(acc.y + b4.y, 0.f) + bfhi(hp.x);
  outv.z = fmaxf(acc.z + b4.z, 0.f) + bflo(hp.y);
  outv.w = fmaxf(acc.w + b4.w, 0.f) + bfhi(hp.y);
  *(ushort4*)&houtb[(size_t)n * HD + lane * 4] =
      make_ushort4(f2bf(outv.x), f2bf(outv.y), f2bf(outv.z), f2bf(outv.w));
}

// ---------------- pooling: per-graph max & sum over bf16 h ----------------
__launch_bounds__(1024)
__global__ void k_pool(const unsigned short* __restrict__ hb, const int* __restrict__ goffs,
                       float* __restrict__ pooled) {
  __shared__ float4 smax[32][32];   // [slot][lane]
  __shared__ float4 ssum[32][32];
  int g = blockIdx.x;
  int slot = threadIdx.x >> 5;
  int lane = threadIdx.x & 31;
  int a = goffs[g], bnd = goffs[g + 1];
  const uint2* hb2 = (const uint2*)hb;

  float4 mx = make_float4(-INFINITY, -INFINITY, -INFINITY, -INFINITY);
  float4 sm = make_float4(0.f, 0.f, 0.f, 0.f);
  for (int i = a + slot; i < bnd; i += 32) {
    uint2 p = hb2[(size_t)i * 32 + lane];
    float4 v = make_float4(bflo(p.x), bfhi(p.x), bflo(p.y), bfhi(p.y));
    MAX4(mx, v);
    ADD4(sm, v);
  }
  smax[slot][lane] = mx;
  ssum[slot][lane] = sm;
  __syncthreads();
#pragma unroll
  for (int off = 16; off >= 1; off >>= 1) {
    if (slot < off) {
      float4 m2 = smax[slot + off][lane];
      float4 s2 = ssum[slot + off][lane];
      float4 m1 = smax[slot][lane];
      float4 s1 = ssum[slot][lane];
      MAX4(m1, m2);
      ADD4(s1, s2);
      smax[slot][lane] = m1;
      ssum[slot][lane] = s1;
    }
    __syncthreads();
  }
  if (slot == 0) {
    *(float4*)&pooled[g * 256 + lane * 4]       = smax[0][lane];
    *(float4*)&pooled[g * 256 + 128 + lane * 4] = ssum[0][lane];
  }
}

// ---------------- head: mol linear+BN+relu, concat, MLP ----------------
__global__ void k_head(const float* __restrict__ pooled, const float* __restrict__ mf,
                       const float* __restrict__ Wm, const float* __restrict__ bm,
                       const float* __restrict__ gamma, const float* __restrict__ beta,
                       const float* __restrict__ W1, const float* __restrict__ b1,
                       const float* __restrict__ W2, const float* __restrict__ b2,
                       float* __restrict__ out) {
  __shared__ float z[288];
  __shared__ float z1[128];
  int g = blockIdx.x, t = threadIdx.x;  // 128 threads
  z[t] = pooled[g * 256 + t];
  z[128 + t] = pooled[g * 256 + 128 + t];
  if (t < NMH) {
    float acc = bm[t];
    for (int k = 0; k < NM; ++k) acc += mf[g * NM + k] * Wm[k * NMH + t];
    acc = acc * gamma[t] + beta[t];
    z[256 + t] = fmaxf(acc, 0.f);
  }
  __syncthreads();
  float acc = b1[t];
  for (int k = 0; k < 288; ++k) acc += z[k] * W1[k * HD + t];
  z1[t] = fmaxf(acc, 0.f);
  __syncthreads();
  if (t < NO) {
    float a2 = b2[t];
    for (int k = 0; k < HD; ++k) a2 += z1[k] * W2[k * NO + t];
    out[g * NO + t] = a2;
  }
}

extern "C" void kernel_launch(void* const* d_in, const int* in_sizes, int n_in,
                              void* d_out, int out_size, void* d_ws, size_t ws_size,
                              hipStream_t stream) {
  const float* x     = (const float*)d_in[0];
  const int*   eidx  = (const int*)d_in[1];
  const int*   batch = (const int*)d_in[2];
  const float* mf    = (const float*)d_in[3];
  const float* Ws    = (const float*)d_in[4];
  const float* bs    = (const float*)d_in[5];
  const float* Wm    = (const float*)d_in[6];
  const float* bm    = (const float*)d_in[7];
  const float* gamma = (const float*)d_in[8];
  const float* beta  = (const float*)d_in[9];
  const float* W1    = (const float*)d_in[10];
  const float* b1    = (const float*)d_in[11];
  const float* W2    = (const float*)d_in[12];
  const float* b2    = (const float*)d_in[13];
  float* out = (float*)d_out;

  const int* src = eidx;
  const int* dst = eidx + NE;

  // workspace carve-out
  char* w = (char*)d_ws;
  size_t off = 0;
  auto alloc = [&](size_t bytes) -> void* {
    void* p = w + off;
    off += (bytes + 255) & ~(size_t)255;
    return p;
  };
  float* dis    = (float*)alloc((size_t)NN * 4);
  unsigned short* xw  = (unsigned short*)alloc((size_t)NN * HD * 2);  // bf16 GEMM out
  unsigned short* xbf = (unsigned short*)alloc((size_t)NN * HD * 2);  // bf16 copy of x
  unsigned short* hbf = (unsigned short*)alloc((size_t)NN * HD * 2);  // bf16 h state
  unsigned short* wT  = (unsigned short*)alloc((size_t)NL * HD * HD * 2);
  int* counts   = (int*)alloc((size_t)NN * 4);
  int* cur      = (int*)alloc((size_t)NN * 4);
  int* rowst    = (int*)alloc((size_t)(NN + 1) * 4);
  uint2* csr    = (uint2*)alloc((size_t)NE * 8);
  int* bsum     = (int*)alloc(256 * 4);
  int* boff     = (int*)alloc(256 * 4);
  int* goffs    = (int*)alloc((size_t)(NB + 1) * 4);
  float* pooled = (float*)alloc((size_t)NB * 256 * 4);
  (void)ws_size;

  const int SB = (NN + 255) / 256;

  hipMemsetAsync(counts, 0, (size_t)NN * 4, stream);
  hipMemsetAsync(cur, 0, (size_t)NN * 4, stream);

  k_hist<<<(NE + 255) / 256, 256, 0, stream>>>(dst, counts);
  k_scan1<<<SB, 256, 0, stream>>>(counts, rowst, bsum, dis);
  k_scan2<<<1, 256, 0, stream>>>(bsum, boff, SB);
  k_scan3<<<SB, 256, 0, stream>>>(counts, rowst, boff);
  k_fill<<<(NE + 255) / 256, 256, 0, stream>>>(src, dst, rowst, dis, cur, csr);

  k_goffs<<<SB, 256, 0, stream>>>(batch, goffs);
  k_tobf<<<((NN * HD / 4) + 255) / 256, 256, 0, stream>>>((const float4*)x, (ushort4*)xbf, NN * HD / 4);
  k_wT<<<(NL * HD * HD + 255) / 256, 256, 0, stream>>>(Ws, wT);

  for (int l = 0; l < NL; ++l) {
    const unsigned short* gin_bf = (l == 0) ? xbf : hbf;
    k_gemm_mfma<<<(NN + 127) / 128, 256, 0, stream>>>(gin_bf, wT + (size_t)l * HD * HD, xw);
    k_agg<<<(NN + 7) / 8, 256, 0, stream>>>(xw, dis, rowst, csr, bs + (size_t)l * HD, gin_bf, hbf);
  }

  k_pool<<<NB, 1024, 0, stream>>>(hbf, goffs, pooled);
  k_head<<<NB, 128, 0, stream>>>(pooled, mf, Wm, bm, gamma, beta, W1, b1, W2, b2, out);
}

// Round 9
// 282.983 us; speedup vs baseline: 1.7546x; 1.0302x over previous
//
#include <hip/hip_runtime.h>
#include <hip/hip_fp16.h>
#include <math.h>

// Problem constants (fixed by the reference)
static constexpr int NN  = 50000;   // nodes
static constexpr int NE  = 600000;  // edges
static constexpr int HD  = 128;     // feature dim
static constexpr int NL  = 4;       // layers
static constexpr int NB  = 256;     // graphs
static constexpr int NM  = 200;     // molecule features
static constexpr int NO  = 12;      // out features
static constexpr int NMH = 32;      // molecular head width

#define MAX4(ac, b) { (ac).x = fmaxf((ac).x,(b).x); (ac).y = fmaxf((ac).y,(b).y); (ac).z = fmaxf((ac).z,(b).z); (ac).w = fmaxf((ac).w,(b).w); }
#define ADD4(ac, b) { (ac).x += (b).x; (ac).y += (b).y; (ac).z += (b).z; (ac).w += (b).w; }

typedef short bfx8 __attribute__((ext_vector_type(8)));   // 8 bf16 in 4 VGPRs
typedef float f32x4 __attribute__((ext_vector_type(4)));  // MFMA accumulator

__device__ __forceinline__ unsigned short f2bf(float f) {   // RNE float->bf16
  unsigned int u = __float_as_uint(f);
  unsigned int r = (u + 0x7fffu + ((u >> 16) & 1u)) >> 16;
  return (unsigned short)r;
}
__device__ __forceinline__ float bflo(unsigned int p) { return __uint_as_float(p << 16); }
__device__ __forceinline__ float bfhi(unsigned int p) { return __uint_as_float(p & 0xffff0000u); }
__device__ __forceinline__ float h2f_hi(unsigned e) {       // fp16 bits in e[31:16] -> float
  return __half2float(__ushort_as_half((unsigned short)(e >> 16)));
}

// ---------------- CSR build ----------------
__global__ void k_hist(const int* __restrict__ dst, int* __restrict__ counts) {
  int e = blockIdx.x * blockDim.x + threadIdx.x;
  if (e < NE) atomicAdd(&counts[dst[e]], 1);
}

// scan1 also computes dis = rsqrt(deg+1)
__global__ void k_scan1(const int* __restrict__ counts, int* __restrict__ incl,
                        int* __restrict__ bsum, float* __restrict__ dis) {
  __shared__ int s[256];
  int i = blockIdx.x * 256 + threadIdx.x;
  int v = (i < NN) ? counts[i] : 0;
  if (i < NN) dis[i] = rsqrtf((float)(v + 1));
  s[threadIdx.x] = v;
  __syncthreads();
  for (int off = 1; off < 256; off <<= 1) {
    int t = (threadIdx.x >= off) ? s[threadIdx.x - off] : 0;
    __syncthreads();
    s[threadIdx.x] += t;
    __syncthreads();
  }
  if (i < NN) incl[i] = s[threadIdx.x];
  if (threadIdx.x == 255) bsum[blockIdx.x] = s[255];
}

__global__ void k_scan2(const int* __restrict__ bsum, int* __restrict__ boff, int nblocks) {
  __shared__ int s[256];
  int v = (threadIdx.x < nblocks) ? bsum[threadIdx.x] : 0;
  s[threadIdx.x] = v;
  __syncthreads();
  for (int off = 1; off < 256; off <<= 1) {
    int t = (threadIdx.x >= off) ? s[threadIdx.x - off] : 0;
    __syncthreads();
    s[threadIdx.x] += t;
    __syncthreads();
  }
  boff[threadIdx.x] = s[threadIdx.x] - v;  // exclusive
}

__global__ void k_scan3(const int* __restrict__ counts, int* __restrict__ rowst, const int* __restrict__ boff) {
  int i = blockIdx.x * 256 + threadIdx.x;
  if (i < NN) {
    rowst[i] = rowst[i] - counts[i] + boff[blockIdx.x];  // exclusive global
    if (i == NN - 1) rowst[NN] = NE;
  }
}

// csr entry (4B) = fp16bits(dis[src])<<16 | src   (src < 65536 guaranteed: NN=50000)
__global__ void k_fill(const int* __restrict__ src, const int* __restrict__ dst,
                       const int* __restrict__ rowst, const float* __restrict__ dis,
                       int* __restrict__ cur, unsigned* __restrict__ csr) {
  int e = blockIdx.x * blockDim.x + threadIdx.x;
  if (e < NE) {
    int d = dst[e];
    int s = src[e];
    int p = atomicAdd(&cur[d], 1);
    unsigned hb = (unsigned)__half_as_ushort(__float2half(dis[s]));
    csr[rowst[d] + p] = (hb << 16) | (unsigned)s;
  }
}

// ---------------- misc ----------------
__global__ void k_goffs(const int* __restrict__ batch, int* __restrict__ goffs) {
  int i = blockIdx.x * blockDim.x + threadIdx.x;
  if (i >= NN) return;
  int b = batch[i];
  if (i == 0) {
    for (int g = 0; g <= b; ++g) goffs[g] = 0;
  } else {
    int pb = batch[i - 1];
    for (int g = pb + 1; g <= b; ++g) goffs[g] = i;
  }
  if (i == NN - 1) goffs[NB] = NN;
}

// fp32 -> bf16 conversion (4 elems/thread)
__global__ void k_tobf(const float4* __restrict__ in, ushort4* __restrict__ outb, int n4) {
  int i = blockIdx.x * blockDim.x + threadIdx.x;
  if (i < n4) {
    float4 v = in[i];
    outb[i] = make_ushort4(f2bf(v.x), f2bf(v.y), f2bf(v.z), f2bf(v.w));
  }
}

// Ws[l][k][n] -> wT[l][n][k] bf16
__global__ void k_wT(const float* __restrict__ Ws, unsigned short* __restrict__ wT) {
  int i = blockIdx.x * blockDim.x + threadIdx.x;
  if (i < NL * HD * HD) {
    int l = i >> 14, rem = i & 16383, n = rem >> 7, k = rem & 127;
    wT[i] = f2bf(Ws[l * 16384 + k * 128 + n]);
  }
}

// ---------------- MFMA GEMM: C[NN,128] = A[NN,128] @ W, A/C bf16, W as WT[n][k] bf16 ----------------
__launch_bounds__(256)
__global__ void k_gemm_mfma(const unsigned short* __restrict__ A,
                            const unsigned short* __restrict__ WT,
                            unsigned short* __restrict__ C) {
  const int wave = threadIdx.x >> 6;
  const int lane = threadIdx.x & 63;
  const int m_base = blockIdx.x * 128 + wave * 32;
  const int lr = lane & 15;       // A row-in-frag / B col-in-frag
  const int kg = lane >> 4;       // k-subgroup: 8 contiguous k elems

  f32x4 acc[2][8];
#pragma unroll
  for (int mi = 0; mi < 2; ++mi)
#pragma unroll
    for (int nj = 0; nj < 8; ++nj) acc[mi][nj] = (f32x4){0.f, 0.f, 0.f, 0.f};

  int ra0 = m_base + lr;       if (ra0 > NN - 1) ra0 = NN - 1;
  int ra1 = m_base + 16 + lr;  if (ra1 > NN - 1) ra1 = NN - 1;

#pragma unroll
  for (int kb = 0; kb < 4; ++kb) {
    const int k0 = kb * 32 + kg * 8;
    bfx8 a0 = *(const bfx8*)&A[(size_t)ra0 * HD + k0];
    bfx8 a1 = *(const bfx8*)&A[(size_t)ra1 * HD + k0];
#pragma unroll
    for (int nj = 0; nj < 8; ++nj) {
      bfx8 b = *(const bfx8*)&WT[(nj * 16 + lr) * HD + k0];
      acc[0][nj] = __builtin_amdgcn_mfma_f32_16x16x32_bf16(a0, b, acc[0][nj], 0, 0, 0);
      acc[1][nj] = __builtin_amdgcn_mfma_f32_16x16x32_bf16(a1, b, acc[1][nj], 0, 0, 0);
    }
  }

  // C/D layout: col = lane&15, row = (lane>>4)*4 + reg   [m89 verified]
  const int col = lane & 15;
  const int rbase = (lane >> 4) * 4;
#pragma unroll
  for (int mi = 0; mi < 2; ++mi) {
#pragma unroll
    for (int r = 0; r < 4; ++r) {
      int row = m_base + mi * 16 + rbase + r;
      if (row < NN) {
#pragma unroll
        for (int nj = 0; nj < 8; ++nj) {
          C[(size_t)row * HD + nj * 16 + col] = f2bf(acc[mi][nj][r]);
        }
      }
    }
  }
}

// ---------------- aggregate + bias + relu + residual (all bf16 state) ----------------
#define AGG_EDGE(e, p) { float nm = h2f_hi(e) * dn; \
    acc.x += nm * bflo((p).x); acc.y += nm * bfhi((p).x); \
    acc.z += nm * bflo((p).y); acc.w += nm * bfhi((p).y); }

__global__ void k_agg(const unsigned short* __restrict__ xw, const float* __restrict__ dis,
                      const int* __restrict__ rowst, const unsigned* __restrict__ csr,
                      const float* __restrict__ bias, const unsigned short* __restrict__ hinb,
                      unsigned short* __restrict__ houtb) {
  int g = threadIdx.x >> 5;          // node slot 0..7
  int lane = threadIdx.x & 31;       // feature group: floats lane*4..lane*4+3
  int n = blockIdx.x * 8 + g;
  if (n >= NN) return;

  const uint2* xwb = (const uint2*)xw;   // 8B = 4 bf16 per lane

  float dn = dis[n];
  float4 acc;
  {
    uint2 p = xwb[(size_t)n * 32 + lane];
    float sl = dn * dn;
    acc.x = bflo(p.x) * sl; acc.y = bfhi(p.x) * sl;
    acc.z = bflo(p.y) * sl; acc.w = bfhi(p.y) * sl;
  }

  int s0 = rowst[n], s1 = rowst[n + 1];
  int idx = s0;
  for (; idx + 8 <= s1; idx += 8) {
    unsigned e0 = csr[idx],     e1 = csr[idx + 1], e2 = csr[idx + 2], e3 = csr[idx + 3];
    unsigned e4 = csr[idx + 4], e5 = csr[idx + 5], e6 = csr[idx + 6], e7 = csr[idx + 7];
    uint2 p0 = xwb[(size_t)(e0 & 0xffffu) * 32 + lane];
    uint2 p1 = xwb[(size_t)(e1 & 0xffffu) * 32 + lane];
    uint2 p2 = xwb[(size_t)(e2 & 0xffffu) * 32 + lane];
    uint2 p3 = xwb[(size_t)(e3 & 0xffffu) * 32 + lane];
    uint2 p4 = xwb[(size_t)(e4 & 0xffffu) * 32 + lane];
    uint2 p5 = xwb[(size_t)(e5 & 0xffffu) * 32 + lane];
    uint2 p6 = xwb[(size_t)(e6 & 0xffffu) * 32 + lane];
    uint2 p7 = xwb[(size_t)(e7 & 0xffffu) * 32 + lane];
    AGG_EDGE(e0, p0); AGG_EDGE(e1, p1); AGG_EDGE(e2, p2); AGG_EDGE(e3, p3);
    AGG_EDGE(e4, p4); AGG_EDGE(e5, p5); AGG_EDGE(e6, p6); AGG_EDGE(e7, p7);
  }
  for (; idx + 4 <= s1; idx += 4) {
    unsigned e0 = csr[idx], e1 = csr[idx + 1], e2 = csr[idx + 2], e3 = csr[idx + 3];
    uint2 p0 = xwb[(size_t)(e0 & 0xffffu) * 32 + lane];
    uint2 p1 = xwb[(size_t)(e1 & 0xffffu) * 32 + lane];
    uint2 p2 = xwb[(size_t)(e2 & 0xffffu) * 32 + lane];
    uint2 p3 = xwb[(size_t)(e3 & 0xffffu) * 32 + lane];
    AGG_EDGE(e0, p0); AGG_EDGE(e1, p1); AGG_EDGE(e2, p2); AGG_EDGE(e3, p3);
  }
  for (; idx < s1; ++idx) {
    unsigned e0 = csr[idx];
    uint2 p0 = xwb[(size_t)(e0 & 0xffffu) * 32 + lane];
    AGG_EDGE(e0, p0);
  }

  float4 b4 = *(const float4*)&bias[lane * 4];
  uint2 hp = ((const uint2*)hinb)[(size_t)n * 32 + lane];
  float4 outv;
  outv.x = fmaxf(acc.x + b4.x, 0.f) + bflo(hp.x);
  outv.y = fmaxf(acc.y + b4.y, 0.f) + bfhi(hp.x);
  outv.z = fmaxf(acc.z + b4.z, 0.f) + bflo(hp.y);
  outv.w = fmaxf(acc.w + b4.w, 0.f) + bfhi(hp.y);
  *(ushort4*)&houtb[(size_t)n * HD + lane * 4] =
      make_ushort4(f2bf(outv.x), f2bf(outv.y), f2bf(outv.z), f2bf(outv.w));
}

// ---------------- pooling: per-graph max & sum over bf16 h ----------------
__launch_bounds__(1024)
__global__ void k_pool(const unsigned short* __restrict__ hb, const int* __restrict__ goffs,
                       float* __restrict__ pooled) {
  __shared__ float4 smax[32][32];   // [slot][lane]
  __shared__ float4 ssum[32][32];
  int g = blockIdx.x;
  int slot = threadIdx.x >> 5;
  int lane = threadIdx.x & 31;
  int a = goffs[g], bnd = goffs[g + 1];
  const uint2* hb2 = (const uint2*)hb;

  float4 mx = make_float4(-INFINITY, -INFINITY, -INFINITY, -INFINITY);
  float4 sm = make_float4(0.f, 0.f, 0.f, 0.f);
  for (int i = a + slot; i < bnd; i += 32) {
    uint2 p = hb2[(size_t)i * 32 + lane];
    float4 v = make_float4(bflo(p.x), bfhi(p.x), bflo(p.y), bfhi(p.y));
    MAX4(mx, v);
    ADD4(sm, v);
  }
  smax[slot][lane] = mx;
  ssum[slot][lane] = sm;
  __syncthreads();
#pragma unroll
  for (int off = 16; off >= 1; off >>= 1) {
    if (slot < off) {
      float4 m2 = smax[slot + off][lane];
      float4 s2 = ssum[slot + off][lane];
      float4 m1 = smax[slot][lane];
      float4 s1 = ssum[slot][lane];
      MAX4(m1, m2);
      ADD4(s1, s2);
      smax[slot][lane] = m1;
      ssum[slot][lane] = s1;
    }
    __syncthreads();
  }
  if (slot == 0) {
    *(float4*)&pooled[g * 256 + lane * 4]       = smax[0][lane];
    *(float4*)&pooled[g * 256 + 128 + lane * 4] = ssum[0][lane];
  }
}

// ---------------- head: mol linear+BN+relu, concat, MLP ----------------
__global__ void k_head(const float* __restrict__ pooled, const float* __restrict__ mf,
                       const float* __restrict__ Wm, const float* __restrict__ bm,
                       const float* __restrict__ gamma, const float* __restrict__ beta,
                       const float* __restrict__ W1, const float* __restrict__ b1,
                       const float* __restrict__ W2, const float* __restrict__ b2,
                       float* __restrict__ out) {
  __shared__ float z[288];
  __shared__ float z1[128];
  int g = blockIdx.x, t = threadIdx.x;  // 128 threads
  z[t] = pooled[g * 256 + t];
  z[128 + t] = pooled[g * 256 + 128 + t];
  if (t < NMH) {
    float acc = bm[t];
    for (int k = 0; k < NM; ++k) acc += mf[g * NM + k] * Wm[k * NMH + t];
    acc = acc * gamma[t] + beta[t];
    z[256 + t] = fmaxf(acc, 0.f);
  }
  __syncthreads();
  float acc = b1[t];
  for (int k = 0; k < 288; ++k) acc += z[k] * W1[k * HD + t];
  z1[t] = fmaxf(acc, 0.f);
  __syncthreads();
  if (t < NO) {
    float a2 = b2[t];
    for (int k = 0; k < HD; ++k) a2 += z1[k] * W2[k * NO + t];
    out[g * NO + t] = a2;
  }
}

extern "C" void kernel_launch(void* const* d_in, const int* in_sizes, int n_in,
                              void* d_out, int out_size, void* d_ws, size_t ws_size,
                              hipStream_t stream) {
  const float* x     = (const float*)d_in[0];
  const int*   eidx  = (const int*)d_in[1];
  const int*   batch = (const int*)d_in[2];
  const float* mf    = (const float*)d_in[3];
  const float* Ws    = (const float*)d_in[4];
  const float* bs    = (const float*)d_in[5];
  const float* Wm    = (const float*)d_in[6];
  const float* bm    = (const float*)d_in[7];
  const float* gamma = (const float*)d_in[8];
  const float* beta  = (const float*)d_in[9];
  const float* W1    = (const float*)d_in[10];
  const float* b1    = (const float*)d_in[11];
  const float* W2    = (const float*)d_in[12];
  const float* b2    = (const float*)d_in[13];
  float* out = (float*)d_out;

  const int* src = eidx;
  const int* dst = eidx + NE;

  // workspace carve-out
  char* w = (char*)d_ws;
  size_t off = 0;
  auto alloc = [&](size_t bytes) -> void* {
    void* p = w + off;
    off += (bytes + 255) & ~(size_t)255;
    return p;
  };
  float* dis    = (float*)alloc((size_t)NN * 4);
  unsigned short* xw  = (unsigned short*)alloc((size_t)NN * HD * 2);  // bf16 GEMM out
  unsigned short* xbf = (unsigned short*)alloc((size_t)NN * HD * 2);  // bf16 copy of x
  unsigned short* hbf = (unsigned short*)alloc((size_t)NN * HD * 2);  // bf16 h state
  unsigned short* wT  = (unsigned short*)alloc((size_t)NL * HD * HD * 2);
  int* counts   = (int*)alloc((size_t)NN * 4);
  int* cur      = (int*)alloc((size_t)NN * 4);
  int* rowst    = (int*)alloc((size_t)(NN + 1) * 4);
  unsigned* csr = (unsigned*)alloc((size_t)NE * 4);
  int* bsum     = (int*)alloc(256 * 4);
  int* boff     = (int*)alloc(256 * 4);
  int* goffs    = (int*)alloc((size_t)(NB + 1) * 4);
  float* pooled = (float*)alloc((size_t)NB * 256 * 4);
  (void)ws_size;

  const int SB = (NN + 255) / 256;

  hipMemsetAsync(counts, 0, (size_t)NN * 4, stream);
  hipMemsetAsync(cur, 0, (size_t)NN * 4, stream);

  k_hist<<<(NE + 255) / 256, 256, 0, stream>>>(dst, counts);
  k_scan1<<<SB, 256, 0, stream>>>(counts, rowst, bsum, dis);
  k_scan2<<<1, 256, 0, stream>>>(bsum, boff, SB);
  k_scan3<<<SB, 256, 0, stream>>>(counts, rowst, boff);
  k_fill<<<(NE + 255) / 256, 256, 0, stream>>>(src, dst, rowst, dis, cur, csr);

  k_goffs<<<SB, 256, 0, stream>>>(batch, goffs);
  k_tobf<<<((NN * HD / 4) + 255) / 256, 256, 0, stream>>>((const float4*)x, (ushort4*)xbf, NN * HD / 4);
  k_wT<<<(NL * HD * HD + 255) / 256, 256, 0, stream>>>(Ws, wT);

  for (int l = 0; l < NL; ++l) {
    const unsigned short* gin_bf = (l == 0) ? xbf : hbf;
    k_gemm_mfma<<<(NN + 127) / 128, 256, 0, stream>>>(gin_bf, wT + (size_t)l * HD * HD, xw);
    k_agg<<<(NN + 7) / 8, 256, 0, stream>>>(xw, dis, rowst, csr, bs + (size_t)l * HD, gin_bf, hbf);
  }

  k_pool<<<NB, 1024, 0, stream>>>(hbf, goffs, pooled);
  k_head<<<NB, 128, 0, stream>>>(pooled, mf, Wm, bm, gamma, beta, W1, b1, W2, b2, out);
}